// Round 6
// baseline (1048.615 us; speedup 1.0000x reference)
//
#include <hip/hip_runtime.h>
#include <math.h>

#define N_NODES 100000
#define N_EDGES 3200000
#define NF 256

typedef unsigned short u16;
typedef unsigned int u32;

typedef __bf16 bf16x8_t __attribute__((ext_vector_type(8)));
typedef float f32x4_t __attribute__((ext_vector_type(4)));
typedef u32 u32x2_t __attribute__((ext_vector_type(2)));
typedef u32 u32x4_t __attribute__((ext_vector_type(4)));

union U8 { uint4 q; u16 s[8]; u32x4_t v; };
union F4U { float4 f; u32x4_t v; };

typedef __attribute__((address_space(1))) const void* as1_cvp;
typedef __attribute__((address_space(3))) void* as3_vp;

__device__ __forceinline__ float bf2f(u16 u) {
  union { u32 i; float f; } v; v.i = ((u32)u) << 16; return v.f;
}
__device__ __forceinline__ u16 f2bf(float f) {
  union { float f; u32 i; } v; v.f = f;
  u32 x = v.i;
  u32 r = (x + 0x7FFFu + ((x >> 16) & 1u)) >> 16;
  return (u16)r;
}
__device__ __forceinline__ float u2f(u32 u) {
  union { u32 i; float f; } v; v.i = u; return v.f;
}

// ---- non-temporal (nt) streaming access helpers: no L2 allocate/pollution ----
__device__ __forceinline__ uint2 nt_load_u2(const uint2* p) {
  u32x2_t t = __builtin_nontemporal_load((const u32x2_t*)p);
  uint2 r; r.x = t.x; r.y = t.y; return r;
}
__device__ __forceinline__ void nt_store_u2(uint2 v, uint2* p) {
  u32x2_t t; t.x = v.x; t.y = v.y;
  __builtin_nontemporal_store(t, (u32x2_t*)p);
}
__device__ __forceinline__ u32x4_t nt_load_u4v(const void* p) {
  return __builtin_nontemporal_load((const u32x4_t*)p);
}
__device__ __forceinline__ void nt_store_u4v(u32x4_t v, void* p) {
  __builtin_nontemporal_store(v, (u32x4_t*)p);
}
__device__ __forceinline__ int nt_load_i(const int* p) { return __builtin_nontemporal_load(p); }
__device__ __forceinline__ void nt_store_i(int v, int* p) { __builtin_nontemporal_store(v, p); }
__device__ __forceinline__ float nt_load_f(const float* p) { return __builtin_nontemporal_load(p); }
__device__ __forceinline__ u16 nt_load_h(const u16* p) { return __builtin_nontemporal_load(p); }

__device__ __forceinline__ void gload_lds16(const u16* g, u16* l) {
  __builtin_amdgcn_global_load_lds((as1_cvp)g, (as3_vp)l, 16, 0, 0);
}

// ---- dtype sniff: bf16-NaN bit patterns appear in f32 mantissa halves only ----
__global__ void sniff_kernel(const u16* __restrict__ xr, int* __restrict__ flag) {
  __shared__ int cnt;
  if (threadIdx.x == 0) cnt = 0;
  __syncthreads();
  int c = 0;
  for (int i = threadIdx.x; i < 65536; i += 256) {
    u16 u = xr[i];
    if ((u & 0x7F80u) == 0x7F80u) c++;
  }
  atomicAdd(&cnt, c);
  __syncthreads();
  if (threadIdx.x == 0) flag[0] = (cnt >= 4) ? 1 : 0;  // 1 => inputs are f32
}

// ---- merged prep: W1/W2 transpose + both bias converts in one dispatch ----
__global__ void prep_wb(const u16* __restrict__ W1u, const float* __restrict__ W1f,
                        const u16* __restrict__ W2u, const float* __restrict__ W2f,
                        const u16* __restrict__ b1u, const float* __restrict__ b1f,
                        const u16* __restrict__ b2u, const float* __restrict__ b2f,
                        const int* __restrict__ flagp,
                        u16* __restrict__ Wt1, u16* __restrict__ Wt2,
                        u16* __restrict__ bb1, u16* __restrict__ bb2) {
  int b = blockIdx.x;
  int t = threadIdx.x;
  int isf = flagp[0];
  if (b < 256) {
    Wt1[t * NF + b] = isf ? f2bf(W1f[b * NF + t]) : W1u[b * NF + t];
  } else if (b < 512) {
    int k = b - 256;
    Wt2[t * NF + k] = isf ? f2bf(W2f[k * NF + t]) : W2u[k * NF + t];
  } else if (b == 512) {
    bb1[t] = isf ? f2bf(b1f[t]) : b1u[t];
  } else {
    bb2[t] = isf ? f2bf(b2f[t]) : b2u[t];
  }
}

// ---- x f32 -> bf16 (only when inputs are f32); 8 elems per thread, NT stream ----
__global__ void conv_x(const float* __restrict__ xf, const int* __restrict__ flagp,
                       u16* __restrict__ xbf) {
  if (!flagp[0]) return;
  size_t i = ((size_t)blockIdx.x * 256 + threadIdx.x) * 8;
  F4U a, b;
  a.v = nt_load_u4v(xf + i);
  b.v = nt_load_u4v(xf + i + 4);
  U8 t;
  t.s[0] = f2bf(a.f.x); t.s[1] = f2bf(a.f.y); t.s[2] = f2bf(a.f.z); t.s[3] = f2bf(a.f.w);
  t.s[4] = f2bf(b.f.x); t.s[5] = f2bf(b.f.y); t.s[6] = f2bf(b.f.z); t.s[7] = f2bf(b.f.w);
  nt_store_u4v(t.v, xbf + i);
}

// ---- counting-sort pipeline: single atomic pass (rank = returned old count) ----
__global__ void hist_rank(const int* __restrict__ dst, int* __restrict__ counts,
                          int* __restrict__ rank) {
  int e = blockIdx.x * 256 + threadIdx.x;
  int d = nt_load_i(dst + e);
  nt_store_i(atomicAdd(&counts[d], 1), rank + e);
}

__global__ void scanA(const int* __restrict__ counts, int* __restrict__ partial) {
  __shared__ int s[256];
  int t = threadIdx.x;
  int gid = blockIdx.x * 256 + t;
  int v = (gid < N_NODES) ? counts[gid] : 0;
  s[t] = v;
  __syncthreads();
  for (int offd = 128; offd > 0; offd >>= 1) {
    if (t < offd) s[t] += s[t + offd];
    __syncthreads();
  }
  if (t == 0) partial[blockIdx.x] = s[0];
}

__global__ void scanB(int* __restrict__ partial) {
  const int NPART = 391;
  __shared__ int s[512];
  int t = threadIdx.x;
  int v = (t < NPART) ? partial[t] : 0;
  s[t] = v;
  __syncthreads();
  for (int offd = 1; offd < 512; offd <<= 1) {
    int x = 0;
    if (t >= offd) x = s[t - offd];
    __syncthreads();
    s[t] += x;
    __syncthreads();
  }
  if (t < NPART) partial[t] = (t == 0) ? 0 : s[t - 1];  // exclusive
}

__global__ void scanC(const int* __restrict__ counts, const int* __restrict__ partial,
                      int* __restrict__ offs) {
  __shared__ int s[256];
  int t = threadIdx.x;
  int b = blockIdx.x;
  int gid = b * 256 + t;
  int v = (gid < N_NODES) ? counts[gid] : 0;
  s[t] = v;
  __syncthreads();
  for (int offd = 1; offd < 256; offd <<= 1) {
    int x = 0;
    if (t >= offd) x = s[t - offd];
    __syncthreads();
    s[t] += x;
    __syncthreads();
  }
  int incl = s[t];
  if (gid < N_NODES) offs[gid] = partial[b] + (incl - v);
  if (gid == N_NODES - 1) offs[N_NODES] = partial[b] + incl;
}

// ---- packed placement: ONE scattered 8B NT store per edge {src, w(f32)} ----
__global__ void place_pack(const int* __restrict__ src, const int* __restrict__ dst,
                           const u16* __restrict__ wu, const float* __restrict__ wf,
                           const int* __restrict__ flagp, const int* __restrict__ offs,
                           const int* __restrict__ rank, uint2* __restrict__ rec) {
  int e = blockIdx.x * 256 + threadIdx.x;
  int d = nt_load_i(dst + e);
  int pos = offs[d] + nt_load_i(rank + e);
  float w = flagp[0] ? nt_load_f(wf + e) : bf2f(nt_load_h(wu + e));
  uint2 r;
  r.x = (u32)nt_load_i(src + e);
  r.y = __float_as_uint(w);
  nt_store_u2(r, rec + pos);
}

// ---- split placement (fallback when ws too small for packed) ----
__global__ void place_full(const int* __restrict__ src, const int* __restrict__ dst,
                           const u16* __restrict__ wu, const float* __restrict__ wf,
                           const int* __restrict__ flagp, const int* __restrict__ offs,
                           const int* __restrict__ rank,
                           int* __restrict__ ssrc, u16* __restrict__ sw) {
  int e = blockIdx.x * 256 + threadIdx.x;
  int pos = offs[dst[e]] + rank[e];
  ssrc[pos] = src[e];
  if (flagp[0]) sw[pos] = f2bf(wf[e]);
  else          sw[pos] = wu[e];
}

__global__ void place_eid(const int* __restrict__ dst, const int* __restrict__ offs,
                          const int* __restrict__ rank, int* __restrict__ seid) {
  int e = blockIdx.x * 256 + threadIdx.x;
  seid[offs[dst[e]] + rank[e]] = e;
}

// ---- bf16 MFMA GEMM: global_load_lds staging, 2-phase double-buffer ----
// C[M,256] = A[M,256] @ W ; A is bf16 (A1 if f32 inputs were pre-converted, else A0)
__global__ __launch_bounds__(256) void gemm_gll(
    const u16* __restrict__ A0, const u16* __restrict__ A1,
    const u16* __restrict__ Bt, u16* __restrict__ C, int M,
    const int* __restrict__ flagp) {
  __shared__ __align__(16) u16 Al[2][128 * 32];  // linear [row][32] (64B rows)
  __shared__ __align__(16) u16 Bl[2][128 * 32];
  const u16* A = flagp[0] ? A1 : A0;
  const int tid = threadIdx.x;
  const int m0 = blockIdx.x * 128;
  const int n0 = blockIdx.y * 128;
  const int lane = tid & 63;
  const int wave = tid >> 6;
  const int wm = (wave & 1) * 64;
  const int wn = (wave >> 1) * 64;
  const int mrow = lane & 15;
  const int grp = lane >> 4;

  f32x4_t acc[4][4];
  const f32x4_t zero = {0.f, 0.f, 0.f, 0.f};
#pragma unroll
  for (int i = 0; i < 4; ++i)
#pragma unroll
    for (int j = 0; j < 4; ++j) acc[i][j] = zero;

  const int rA = lane >> 2;            // 0..15 (row within 1KB chunk)
  const int cA = (lane & 3) * 8;       // u16 col offset: 0,8,16,24
  const int r0 = wave * 32;            // wave-uniform base row (2 chunks of 16)

  auto stage = [&](int buf, int k0) {
#pragma unroll
    for (int c = 0; c < 2; ++c) {
      int rr = r0 + c * 16;            // wave-uniform LDS base row
      int ar = rr + rA;
      int gm = m0 + ar;
      if (gm >= M) gm = 0;             // clamp: garbage rows never stored
      gload_lds16(A + (size_t)gm * NF + k0 + cA, &Al[buf][rr * 32]);
      gload_lds16(Bt + (size_t)(n0 + ar) * NF + k0 + cA, &Bl[buf][rr * 32]);
    }
  };

  stage(0, 0);
  __syncthreads();

  for (int t = 0; t < 8; ++t) {
    int cur = t & 1;
    if (t < 7) stage(cur ^ 1, (t + 1) * 32);  // prefetch next tile (other buf)
    bf16x8_t af[4], bfr[4];
#pragma unroll
    for (int i = 0; i < 4; ++i)
      af[i] = *(const bf16x8_t*)(&Al[cur][(wm + i * 16 + mrow) * 32 + grp * 8]);
#pragma unroll
    for (int j = 0; j < 4; ++j)
      bfr[j] = *(const bf16x8_t*)(&Bl[cur][(wn + j * 16 + mrow) * 32 + grp * 8]);
    // operand-swapped: D = (B^T frag) x (A frag)  =>  lane holds row = mrow,
    // cols = grp*4 + reg (4 consecutive columns) -> packed 8B stores
#pragma unroll
    for (int i = 0; i < 4; ++i)
#pragma unroll
      for (int j = 0; j < 4; ++j)
        acc[i][j] = __builtin_amdgcn_mfma_f32_16x16x32_bf16(bfr[j], af[i], acc[i][j], 0, 0, 0);
    __syncthreads();
  }

#pragma unroll
  for (int i = 0; i < 4; ++i) {
    int row = m0 + wm + i * 16 + mrow;
    if (row >= M) continue;
#pragma unroll
    for (int j = 0; j < 4; ++j) {
      u16 pk[4];
      pk[0] = f2bf(acc[i][j][0]);
      pk[1] = f2bf(acc[i][j][1]);
      pk[2] = f2bf(acc[i][j][2]);
      pk[3] = f2bf(acc[i][j][3]);
      *(uint2*)(C + (size_t)row * NF + n0 + wn + j * 16 + grp * 4) = *(const uint2*)pk;
    }
  }
}

// ---- aggregation from packed records; NT on rec/out, sup stays cached ----
__global__ __launch_bounds__(256) void agg_pack(
    const u16* __restrict__ sup, const int* __restrict__ offs,
    const uint2* __restrict__ rec,
    const u16* __restrict__ bbf, u16* __restrict__ out2, float* __restrict__ out4,
    const int* __restrict__ flagp, int outmask) {
  int node = blockIdx.x * 4 + (threadIdx.x >> 6);
  int lane = threadIdx.x & 63;
  int half = lane >> 5;
  int c0 = (lane & 31) * 8;  // 8 bf16 cols per lane; 32 lanes cover the row
  float a0 = 0.f, a1 = 0.f, a2 = 0.f, a3 = 0.f, a4 = 0.f, a5 = 0.f, a6 = 0.f, a7 = 0.f;
  int eend = offs[node + 1];
  int e = offs[node] + half;  // half 0: even slots, half 1: odd slots

  for (; e + 6 < eend; e += 8) {
    uint2 r0 = nt_load_u2(rec + e), r1 = nt_load_u2(rec + e + 2);
    uint2 r2 = nt_load_u2(rec + e + 4), r3 = nt_load_u2(rec + e + 6);
    float w0 = u2f(r0.y), w1 = u2f(r1.y), w2 = u2f(r2.y), w3 = u2f(r3.y);
    U8 v0, v1, v2, v3;
    v0.q = *(const uint4*)(sup + (((u32)r0.x) << 8) + c0);
    v1.q = *(const uint4*)(sup + (((u32)r1.x) << 8) + c0);
    v2.q = *(const uint4*)(sup + (((u32)r2.x) << 8) + c0);
    v3.q = *(const uint4*)(sup + (((u32)r3.x) << 8) + c0);
    a0 += bf2f(v0.s[0]) * w0; a1 += bf2f(v0.s[1]) * w0; a2 += bf2f(v0.s[2]) * w0; a3 += bf2f(v0.s[3]) * w0;
    a4 += bf2f(v0.s[4]) * w0; a5 += bf2f(v0.s[5]) * w0; a6 += bf2f(v0.s[6]) * w0; a7 += bf2f(v0.s[7]) * w0;
    a0 += bf2f(v1.s[0]) * w1; a1 += bf2f(v1.s[1]) * w1; a2 += bf2f(v1.s[2]) * w1; a3 += bf2f(v1.s[3]) * w1;
    a4 += bf2f(v1.s[4]) * w1; a5 += bf2f(v1.s[5]) * w1; a6 += bf2f(v1.s[6]) * w1; a7 += bf2f(v1.s[7]) * w1;
    a0 += bf2f(v2.s[0]) * w2; a1 += bf2f(v2.s[1]) * w2; a2 += bf2f(v2.s[2]) * w2; a3 += bf2f(v2.s[3]) * w2;
    a4 += bf2f(v2.s[4]) * w2; a5 += bf2f(v2.s[5]) * w2; a6 += bf2f(v2.s[6]) * w2; a7 += bf2f(v2.s[7]) * w2;
    a0 += bf2f(v3.s[0]) * w3; a1 += bf2f(v3.s[1]) * w3; a2 += bf2f(v3.s[2]) * w3; a3 += bf2f(v3.s[3]) * w3;
    a4 += bf2f(v3.s[4]) * w3; a5 += bf2f(v3.s[5]) * w3; a6 += bf2f(v3.s[6]) * w3; a7 += bf2f(v3.s[7]) * w3;
  }
  for (; e < eend; e += 2) {
    uint2 r0 = nt_load_u2(rec + e);
    float w0 = u2f(r0.y);
    U8 v0;
    v0.q = *(const uint4*)(sup + (((u32)r0.x) << 8) + c0);
    a0 += bf2f(v0.s[0]) * w0; a1 += bf2f(v0.s[1]) * w0; a2 += bf2f(v0.s[2]) * w0; a3 += bf2f(v0.s[3]) * w0;
    a4 += bf2f(v0.s[4]) * w0; a5 += bf2f(v0.s[5]) * w0; a6 += bf2f(v0.s[6]) * w0; a7 += bf2f(v0.s[7]) * w0;
  }

  // combine the two half-wave partial sums
  a0 += __shfl_xor(a0, 32); a1 += __shfl_xor(a1, 32);
  a2 += __shfl_xor(a2, 32); a3 += __shfl_xor(a3, 32);
  a4 += __shfl_xor(a4, 32); a5 += __shfl_xor(a5, 32);
  a6 += __shfl_xor(a6, 32); a7 += __shfl_xor(a7, 32);

  if (half == 0) {
    U8 bv; bv.q = *(const uint4*)(bbf + c0);
    float r0 = a0 + bf2f(bv.s[0]);
    float r1 = a1 + bf2f(bv.s[1]);
    float r2 = a2 + bf2f(bv.s[2]);
    float r3 = a3 + bf2f(bv.s[3]);
    float r4 = a4 + bf2f(bv.s[4]);
    float r5 = a5 + bf2f(bv.s[5]);
    float r6 = a6 + bf2f(bv.s[6]);
    float r7 = a7 + bf2f(bv.s[7]);
    r0 = r0 > 0.f ? r0 : expm1f(r0);
    r1 = r1 > 0.f ? r1 : expm1f(r1);
    r2 = r2 > 0.f ? r2 : expm1f(r2);
    r3 = r3 > 0.f ? r3 : expm1f(r3);
    r4 = r4 > 0.f ? r4 : expm1f(r4);
    r5 = r5 > 0.f ? r5 : expm1f(r5);
    r6 = r6 > 0.f ? r6 : expm1f(r6);
    r7 = r7 > 0.f ? r7 : expm1f(r7);
    if (outmask && flagp[0]) {
      F4U o4a, o4b;
      o4a.f.x = r0; o4a.f.y = r1; o4a.f.z = r2; o4a.f.w = r3;
      o4b.f.x = r4; o4b.f.y = r5; o4b.f.z = r6; o4b.f.w = r7;
      nt_store_u4v(o4a.v, out4 + (size_t)node * NF + c0);
      nt_store_u4v(o4b.v, out4 + (size_t)node * NF + c0 + 4);
    } else {
      U8 o;
      o.s[0] = f2bf(r0); o.s[1] = f2bf(r1); o.s[2] = f2bf(r2); o.s[3] = f2bf(r3);
      o.s[4] = f2bf(r4); o.s[5] = f2bf(r5); o.s[6] = f2bf(r6); o.s[7] = f2bf(r7);
      nt_store_u4v(o.v, out2 + (size_t)node * NF + c0);
    }
  }
}

// ---- split-stream aggregation (fallback) ----
__global__ __launch_bounds__(256) void agg_full(
    const u16* __restrict__ sup, const int* __restrict__ offs,
    const int* __restrict__ ssrc, const u16* __restrict__ sw,
    const u16* __restrict__ bbf, u16* __restrict__ out2, float* __restrict__ out4,
    const int* __restrict__ flagp, int outmask) {
  int node = blockIdx.x * 4 + (threadIdx.x >> 6);
  int lane = threadIdx.x & 63;
  int half = lane >> 5;
  int c0 = (lane & 31) * 8;
  float a0 = 0.f, a1 = 0.f, a2 = 0.f, a3 = 0.f, a4 = 0.f, a5 = 0.f, a6 = 0.f, a7 = 0.f;
  int eend = offs[node + 1];
  int e = offs[node] + half;

  for (; e + 6 < eend; e += 8) {
    int s0 = ssrc[e], s1 = ssrc[e + 2], s2 = ssrc[e + 4], s3 = ssrc[e + 6];
    float w0 = bf2f(sw[e]), w1 = bf2f(sw[e + 2]), w2 = bf2f(sw[e + 4]), w3 = bf2f(sw[e + 6]);
    U8 v0, v1, v2, v3;
    v0.q = *(const uint4*)(sup + (((u32)s0) << 8) + c0);
    v1.q = *(const uint4*)(sup + (((u32)s1) << 8) + c0);
    v2.q = *(const uint4*)(sup + (((u32)s2) << 8) + c0);
    v3.q = *(const uint4*)(sup + (((u32)s3) << 8) + c0);
    a0 += bf2f(v0.s[0]) * w0; a1 += bf2f(v0.s[1]) * w0; a2 += bf2f(v0.s[2]) * w0; a3 += bf2f(v0.s[3]) * w0;
    a4 += bf2f(v0.s[4]) * w0; a5 += bf2f(v0.s[5]) * w0; a6 += bf2f(v0.s[6]) * w0; a7 += bf2f(v0.s[7]) * w0;
    a0 += bf2f(v1.s[0]) * w1; a1 += bf2f(v1.s[1]) * w1; a2 += bf2f(v1.s[2]) * w1; a3 += bf2f(v1.s[3]) * w1;
    a4 += bf2f(v1.s[4]) * w1; a5 += bf2f(v1.s[5]) * w1; a6 += bf2f(v1.s[6]) * w1; a7 += bf2f(v1.s[7]) * w1;
    a0 += bf2f(v2.s[0]) * w2; a1 += bf2f(v2.s[1]) * w2; a2 += bf2f(v2.s[2]) * w2; a3 += bf2f(v2.s[3]) * w2;
    a4 += bf2f(v2.s[4]) * w2; a5 += bf2f(v2.s[5]) * w2; a6 += bf2f(v2.s[6]) * w2; a7 += bf2f(v2.s[7]) * w2;
    a0 += bf2f(v3.s[0]) * w3; a1 += bf2f(v3.s[1]) * w3; a2 += bf2f(v3.s[2]) * w3; a3 += bf2f(v3.s[3]) * w3;
    a4 += bf2f(v3.s[4]) * w3; a5 += bf2f(v3.s[5]) * w3; a6 += bf2f(v3.s[6]) * w3; a7 += bf2f(v3.s[7]) * w3;
  }
  for (; e < eend; e += 2) {
    int s0 = ssrc[e];
    float w0 = bf2f(sw[e]);
    U8 v0;
    v0.q = *(const uint4*)(sup + (((u32)s0) << 8) + c0);
    a0 += bf2f(v0.s[0]) * w0; a1 += bf2f(v0.s[1]) * w0; a2 += bf2f(v0.s[2]) * w0; a3 += bf2f(v0.s[3]) * w0;
    a4 += bf2f(v0.s[4]) * w0; a5 += bf2f(v0.s[5]) * w0; a6 += bf2f(v0.s[6]) * w0; a7 += bf2f(v0.s[7]) * w0;
  }

  a0 += __shfl_xor(a0, 32); a1 += __shfl_xor(a1, 32);
  a2 += __shfl_xor(a2, 32); a3 += __shfl_xor(a3, 32);
  a4 += __shfl_xor(a4, 32); a5 += __shfl_xor(a5, 32);
  a6 += __shfl_xor(a6, 32); a7 += __shfl_xor(a7, 32);

  if (half == 0) {
    U8 bv; bv.q = *(const uint4*)(bbf + c0);
    float r0 = a0 + bf2f(bv.s[0]);
    float r1 = a1 + bf2f(bv.s[1]);
    float r2 = a2 + bf2f(bv.s[2]);
    float r3 = a3 + bf2f(bv.s[3]);
    float r4 = a4 + bf2f(bv.s[4]);
    float r5 = a5 + bf2f(bv.s[5]);
    float r6 = a6 + bf2f(bv.s[6]);
    float r7 = a7 + bf2f(bv.s[7]);
    r0 = r0 > 0.f ? r0 : expm1f(r0);
    r1 = r1 > 0.f ? r1 : expm1f(r1);
    r2 = r2 > 0.f ? r2 : expm1f(r2);
    r3 = r3 > 0.f ? r3 : expm1f(r3);
    r4 = r4 > 0.f ? r4 : expm1f(r4);
    r5 = r5 > 0.f ? r5 : expm1f(r5);
    r6 = r6 > 0.f ? r6 : expm1f(r6);
    r7 = r7 > 0.f ? r7 : expm1f(r7);
    if (outmask && flagp[0]) {
      float4 o4a, o4b;
      o4a.x = r0; o4a.y = r1; o4a.z = r2; o4a.w = r3;
      o4b.x = r4; o4b.y = r5; o4b.z = r6; o4b.w = r7;
      *(float4*)(out4 + (size_t)node * NF + c0) = o4a;
      *(float4*)(out4 + (size_t)node * NF + c0 + 4) = o4b;
    } else {
      U8 o;
      o.s[0] = f2bf(r0); o.s[1] = f2bf(r1); o.s[2] = f2bf(r2); o.s[3] = f2bf(r3);
      o.s[4] = f2bf(r4); o.s[5] = f2bf(r5); o.s[6] = f2bf(r6); o.s[7] = f2bf(r7);
      *(uint4*)(out2 + (size_t)node * NF + c0) = o.q;
    }
  }
}

// ---- compact variant: sorted edge-id, indirect to esrc/ew (small-ws fallback) ----
__global__ __launch_bounds__(256) void agg_eid(
    const u16* __restrict__ sup, const int* __restrict__ offs,
    const int* __restrict__ seid, const int* __restrict__ esrc,
    const u16* __restrict__ ewu, const float* __restrict__ ewf,
    const u16* __restrict__ bbf, u16* __restrict__ out2, float* __restrict__ out4,
    const int* __restrict__ flagp, int outmask) {
  int node = blockIdx.x * 4 + (threadIdx.x >> 6);
  int lane = threadIdx.x & 63;
  int c0 = lane * 4;
  int isf = flagp[0];
  float a0 = 0.f, a1 = 0.f, a2 = 0.f, a3 = 0.f;
  int e = offs[node];
  int eend = offs[node + 1];
  for (; e < eend; ++e) {
    int eid = seid[e];
    int src = esrc[eid];
    float w = isf ? ewf[eid] : bf2f(ewu[eid]);
    ushort4 v = *(const ushort4*)(sup + (size_t)src * NF + c0);
    a0 += bf2f(v.x) * w;
    a1 += bf2f(v.y) * w;
    a2 += bf2f(v.z) * w;
    a3 += bf2f(v.w) * w;
  }
  ushort4 bv = *(const ushort4*)(bbf + c0);
  float r0 = a0 + bf2f(bv.x);
  float r1 = a1 + bf2f(bv.y);
  float r2 = a2 + bf2f(bv.z);
  float r3 = a3 + bf2f(bv.w);
  r0 = r0 > 0.f ? r0 : expm1f(r0);
  r1 = r1 > 0.f ? r1 : expm1f(r1);
  r2 = r2 > 0.f ? r2 : expm1f(r2);
  r3 = r3 > 0.f ? r3 : expm1f(r3);
  if (outmask && isf) {
    float4 o4;
    o4.x = r0; o4.y = r1; o4.z = r2; o4.w = r3;
    *(float4*)(out4 + (size_t)node * NF + c0) = o4;
  } else {
    ushort4 o;
    o.x = f2bf(r0); o.y = f2bf(r1); o.z = f2bf(r2); o.w = f2bf(r3);
    *(ushort4*)(out2 + (size_t)node * NF + c0) = o;
  }
}

extern "C" void kernel_launch(void* const* d_in, const int* in_sizes, int n_in,
                              void* d_out, int out_size, void* d_ws, size_t ws_size,
                              hipStream_t stream) {
  const u16* x2    = (const u16*)d_in[0];
  const float* x4  = (const float*)d_in[0];
  const u16* W1u   = (const u16*)d_in[1];
  const float* W1f = (const float*)d_in[1];
  const u16* b1u   = (const u16*)d_in[2];
  const float* b1f = (const float*)d_in[2];
  const u16* W2u   = (const u16*)d_in[3];
  const float* W2f = (const float*)d_in[3];
  const u16* b2u   = (const u16*)d_in[4];
  const float* b2f = (const float*)d_in[4];
  const u16* ewu   = (const u16*)d_in[5];
  const float* ewf = (const float*)d_in[5];
  const int* esrc  = (const int*)d_in[6];
  const int* edst  = (const int*)d_in[7];
  u16* out2  = (u16*)d_out;
  float* out4 = (float*)d_out;

  // explicit workspace layout (all offsets 256B-aligned)
  char* ws = (char*)d_ws;
  size_t oWt1     = 0;                      // 131072
  size_t oWt2     = 131072;                 // 131072
  size_t oSup     = 262144;                 // 51,200,000 (also hosts rank[] pre-GEMM1)
  size_t oCounts  = 51462144;               // 400,384
  size_t oOffs    = 51862528;               // 400,384
  size_t oPartial = 52663296;               // 2048
  size_t oFlag    = 52665344;               // 256
  size_t oBb1     = 52665600;               // 1024
  size_t oBb2     = 52666624;               // 1024
  size_t oTail    = 52667648;
  size_t need_pack  = oTail + (size_t)N_EDGES * 8;            // packed records
  size_t need_split = oTail + 12800000 + 6400000;             // ssrc + sw

  u16* Wt1     = (u16*)(ws + oWt1);
  u16* Wt2     = (u16*)(ws + oWt2);
  u16* sup     = (u16*)(ws + oSup);
  int* rank    = (int*)(ws + oSup);   // dead before gemm1 writes sup
  int* counts  = (int*)(ws + oCounts);
  int* offs    = (int*)(ws + oOffs);
  int* partial = (int*)(ws + oPartial);
  int* flag    = (int*)(ws + oFlag);
  u16* bb1     = (u16*)(ws + oBb1);
  u16* bb2     = (u16*)(ws + oBb2);

  // d_out doubles as scratch: lower half = h1 (layer-1 bf16 activation),
  // upper half = xbf (bf16-converted x; dead after gemm1; only used when flag=1,
  // in which case d_out is the 102.4MB f32 buffer so the upper half exists).
  u16* h1  = out2;
  u16* xbf = (u16*)((char*)d_out + (size_t)N_NODES * NF * 2);

  sniff_kernel<<<1, 256, 0, stream>>>(x2, flag);
  hipMemsetAsync(counts, 0, (size_t)N_NODES * 4, stream);
  prep_wb<<<514, 256, 0, stream>>>(W1u, W1f, W2u, W2f, b1u, b1f, b2u, b2f,
                                   flag, Wt1, Wt2, bb1, bb2);
  conv_x<<<N_NODES * NF / (256 * 8), 256, 0, stream>>>(x4, flag, xbf);
  hist_rank<<<N_EDGES / 256, 256, 0, stream>>>(edst, counts, rank);
  scanA<<<391, 256, 0, stream>>>(counts, partial);
  scanB<<<1, 512, 0, stream>>>(partial);
  scanC<<<391, 256, 0, stream>>>(counts, partial, offs);

  dim3 ggrid((N_NODES + 127) / 128, 2);

  if (ws_size >= need_pack) {
    uint2* rec = (uint2*)(ws + oTail);
    place_pack<<<N_EDGES / 256, 256, 0, stream>>>(esrc, edst, ewu, ewf, flag, offs, rank, rec);
    gemm_gll<<<ggrid, 256, 0, stream>>>(x2, xbf, Wt1, sup, N_NODES, flag);
    agg_pack<<<N_NODES / 4, 256, 0, stream>>>(sup, offs, rec, bb1, h1, out4, flag, 0);
    gemm_gll<<<ggrid, 256, 0, stream>>>(h1, h1, Wt2, sup, N_NODES, flag);
    agg_pack<<<N_NODES / 4, 256, 0, stream>>>(sup, offs, rec, bb2, out2, out4, flag, 1);
  } else if (ws_size >= need_split) {
    int* ssrc = (int*)(ws + oTail);
    u16* sw   = (u16*)(ws + oTail + 12800000);
    place_full<<<N_EDGES / 256, 256, 0, stream>>>(esrc, edst, ewu, ewf, flag, offs, rank, ssrc, sw);
    gemm_gll<<<ggrid, 256, 0, stream>>>(x2, xbf, Wt1, sup, N_NODES, flag);
    agg_full<<<N_NODES / 4, 256, 0, stream>>>(sup, offs, ssrc, sw, bb1, h1, out4, flag, 0);
    gemm_gll<<<ggrid, 256, 0, stream>>>(h1, h1, Wt2, sup, N_NODES, flag);
    agg_full<<<N_NODES / 4, 256, 0, stream>>>(sup, offs, ssrc, sw, bb2, out2, out4, flag, 1);
  } else {
    int* seid = (int*)(ws + oTail);
    place_eid<<<N_EDGES / 256, 256, 0, stream>>>(edst, offs, rank, seid);
    gemm_gll<<<ggrid, 256, 0, stream>>>(x2, xbf, Wt1, sup, N_NODES, flag);
    agg_eid<<<N_NODES / 4, 256, 0, stream>>>(sup, offs, seid, esrc, ewu, ewf, bb1, h1, out4, flag, 0);
    gemm_gll<<<ggrid, 256, 0, stream>>>(h1, h1, Wt2, sup, N_NODES, flag);
    agg_eid<<<N_NODES / 4, 256, 0, stream>>>(sup, offs, seid, esrc, ewu, ewf, bb2, out2, out4, flag, 1);
  }
}

// Round 7
// 971.265 us; speedup vs baseline: 1.0796x; 1.0796x over previous
//
#include <hip/hip_runtime.h>
#include <math.h>

#define N_NODES 100000
#define N_EDGES 3200000
#define NF 256

typedef unsigned short u16;
typedef unsigned int u32;

typedef __bf16 bf16x8_t __attribute__((ext_vector_type(8)));
typedef float f32x4_t __attribute__((ext_vector_type(4)));

union U8 { uint4 q; u16 s[8]; };

typedef __attribute__((address_space(1))) const void* as1_cvp;
typedef __attribute__((address_space(3))) void* as3_vp;

__device__ __forceinline__ float bf2f(u16 u) {
  union { u32 i; float f; } v; v.i = ((u32)u) << 16; return v.f;
}
__device__ __forceinline__ u16 f2bf(float f) {
  union { float f; u32 i; } v; v.f = f;
  u32 x = v.i;
  u32 r = (x + 0x7FFFu + ((x >> 16) & 1u)) >> 16;
  return (u16)r;
}
__device__ __forceinline__ float u2f(u32 u) {
  union { u32 i; float f; } v; v.i = u; return v.f;
}

__device__ __forceinline__ void gload_lds16(const u16* g, u16* l) {
  __builtin_amdgcn_global_load_lds((as1_cvp)g, (as3_vp)l, 16, 0, 0);
}

// ---- dtype sniff: bf16-NaN bit patterns appear in f32 mantissa halves only ----
__global__ void sniff_kernel(const u16* __restrict__ xr, int* __restrict__ flag) {
  __shared__ int cnt;
  if (threadIdx.x == 0) cnt = 0;
  __syncthreads();
  int c = 0;
  for (int i = threadIdx.x; i < 65536; i += 256) {
    u16 u = xr[i];
    if ((u & 0x7F80u) == 0x7F80u) c++;
  }
  atomicAdd(&cnt, c);
  __syncthreads();
  if (threadIdx.x == 0) flag[0] = (cnt >= 4) ? 1 : 0;  // 1 => inputs are f32
}

// ---- fused prep: hist_rank (12500 blk) + conv_x (12500 blk) + W/b prep (514 blk) ----
// All three are mutually independent; hist starts first (atomic-latency-bound),
// conv_x streaming waves co-schedule to hide it.
__global__ void prep_all(const int* __restrict__ dst, int* __restrict__ counts,
                         int* __restrict__ rank,
                         const float* __restrict__ xf, u16* __restrict__ xbf,
                         const u16* __restrict__ W1u, const float* __restrict__ W1f,
                         const u16* __restrict__ W2u, const float* __restrict__ W2f,
                         const u16* __restrict__ b1u, const float* __restrict__ b1f,
                         const u16* __restrict__ b2u, const float* __restrict__ b2f,
                         const int* __restrict__ flagp,
                         u16* __restrict__ Wt1, u16* __restrict__ Wt2,
                         u16* __restrict__ bb1, u16* __restrict__ bb2) {
  int b = blockIdx.x;
  int t = threadIdx.x;
  if (b < 12500) {
    // hist_rank
    int e = b * 256 + t;
    rank[e] = atomicAdd(&counts[dst[e]], 1);
  } else if (b < 25000) {
    // conv_x: 8 elems/thread
    if (!flagp[0]) return;
    size_t i = ((size_t)(b - 12500) * 256 + t) * 8;
    float4 a = *(const float4*)(xf + i);
    float4 c = *(const float4*)(xf + i + 4);
    U8 o;
    o.s[0] = f2bf(a.x); o.s[1] = f2bf(a.y); o.s[2] = f2bf(a.z); o.s[3] = f2bf(a.w);
    o.s[4] = f2bf(c.x); o.s[5] = f2bf(c.y); o.s[6] = f2bf(c.z); o.s[7] = f2bf(c.w);
    *(uint4*)(xbf + i) = o.q;
  } else {
    int pb = b - 25000;
    int isf = flagp[0];
    if (pb < 256) {
      Wt1[t * NF + pb] = isf ? f2bf(W1f[pb * NF + t]) : W1u[pb * NF + t];
    } else if (pb < 512) {
      int k = pb - 256;
      Wt2[t * NF + k] = isf ? f2bf(W2f[k * NF + t]) : W2u[k * NF + t];
    } else if (pb == 512) {
      bb1[t] = isf ? f2bf(b1f[t]) : b1u[t];
    } else {
      bb2[t] = isf ? f2bf(b2f[t]) : b2u[t];
    }
  }
}

__global__ void scanA(const int* __restrict__ counts, int* __restrict__ partial) {
  __shared__ int s[256];
  int t = threadIdx.x;
  int gid = blockIdx.x * 256 + t;
  int v = (gid < N_NODES) ? counts[gid] : 0;
  s[t] = v;
  __syncthreads();
  for (int offd = 128; offd > 0; offd >>= 1) {
    if (t < offd) s[t] += s[t + offd];
    __syncthreads();
  }
  if (t == 0) partial[blockIdx.x] = s[0];
}

__global__ void scanB(int* __restrict__ partial) {
  const int NPART = 391;
  __shared__ int s[512];
  int t = threadIdx.x;
  int v = (t < NPART) ? partial[t] : 0;
  s[t] = v;
  __syncthreads();
  for (int offd = 1; offd < 512; offd <<= 1) {
    int x = 0;
    if (t >= offd) x = s[t - offd];
    __syncthreads();
    s[t] += x;
    __syncthreads();
  }
  if (t < NPART) partial[t] = (t == 0) ? 0 : s[t - 1];  // exclusive
}

__global__ void scanC(const int* __restrict__ counts, const int* __restrict__ partial,
                      int* __restrict__ offs) {
  __shared__ int s[256];
  int t = threadIdx.x;
  int b = blockIdx.x;
  int gid = b * 256 + t;
  int v = (gid < N_NODES) ? counts[gid] : 0;
  s[t] = v;
  __syncthreads();
  for (int offd = 1; offd < 256; offd <<= 1) {
    int x = 0;
    if (t >= offd) x = s[t - offd];
    __syncthreads();
    s[t] += x;
    __syncthreads();
  }
  int incl = s[t];
  if (gid < N_NODES) offs[gid] = partial[b] + (incl - v);
  if (gid == N_NODES - 1) offs[N_NODES] = partial[b] + incl;
}

// ---- packed placement: ONE scattered 8B store per edge {src, w(f32)} ----
__global__ void place_pack(const int* __restrict__ src, const int* __restrict__ dst,
                           const u16* __restrict__ wu, const float* __restrict__ wf,
                           const int* __restrict__ flagp, const int* __restrict__ offs,
                           const int* __restrict__ rank, uint2* __restrict__ rec) {
  int e = blockIdx.x * 256 + threadIdx.x;
  int pos = offs[dst[e]] + rank[e];
  float w = flagp[0] ? wf[e] : bf2f(wu[e]);
  uint2 r;
  r.x = (u32)src[e];
  r.y = __float_as_uint(w);
  rec[pos] = r;
}

// ---- split placement (fallback when ws too small for packed) ----
__global__ void place_full(const int* __restrict__ src, const int* __restrict__ dst,
                           const u16* __restrict__ wu, const float* __restrict__ wf,
                           const int* __restrict__ flagp, const int* __restrict__ offs,
                           const int* __restrict__ rank,
                           int* __restrict__ ssrc, u16* __restrict__ sw) {
  int e = blockIdx.x * 256 + threadIdx.x;
  int pos = offs[dst[e]] + rank[e];
  ssrc[pos] = src[e];
  if (flagp[0]) sw[pos] = f2bf(wf[e]);
  else          sw[pos] = wu[e];
}

__global__ void place_eid(const int* __restrict__ dst, const int* __restrict__ offs,
                          const int* __restrict__ rank, int* __restrict__ seid) {
  int e = blockIdx.x * 256 + threadIdx.x;
  seid[offs[dst[e]] + rank[e]] = e;
}

// ---- bf16 MFMA GEMM: global_load_lds staging, 2-phase double-buffer ----
// C[M,256] = A[M,256] @ W ; A is bf16 (A1 if f32 inputs were pre-converted, else A0)
__global__ __launch_bounds__(256) void gemm_gll(
    const u16* __restrict__ A0, const u16* __restrict__ A1,
    const u16* __restrict__ Bt, u16* __restrict__ C, int M,
    const int* __restrict__ flagp) {
  __shared__ __align__(16) u16 Al[2][128 * 32];  // linear [row][32] (64B rows)
  __shared__ __align__(16) u16 Bl[2][128 * 32];
  const u16* A = flagp[0] ? A1 : A0;
  const int tid = threadIdx.x;
  const int m0 = blockIdx.x * 128;
  const int n0 = blockIdx.y * 128;
  const int lane = tid & 63;
  const int wave = tid >> 6;
  const int wm = (wave & 1) * 64;
  const int wn = (wave >> 1) * 64;
  const int mrow = lane & 15;
  const int grp = lane >> 4;

  f32x4_t acc[4][4];
  const f32x4_t zero = {0.f, 0.f, 0.f, 0.f};
#pragma unroll
  for (int i = 0; i < 4; ++i)
#pragma unroll
    for (int j = 0; j < 4; ++j) acc[i][j] = zero;

  const int rA = lane >> 2;            // 0..15 (row within 1KB chunk)
  const int cA = (lane & 3) * 8;       // u16 col offset: 0,8,16,24
  const int r0 = wave * 32;            // wave-uniform base row (2 chunks of 16)

  auto stage = [&](int buf, int k0) {
#pragma unroll
    for (int c = 0; c < 2; ++c) {
      int rr = r0 + c * 16;            // wave-uniform LDS base row
      int ar = rr + rA;
      int gm = m0 + ar;
      if (gm >= M) gm = 0;             // clamp: garbage rows never stored
      gload_lds16(A + (size_t)gm * NF + k0 + cA, &Al[buf][rr * 32]);
      gload_lds16(Bt + (size_t)(n0 + ar) * NF + k0 + cA, &Bl[buf][rr * 32]);
    }
  };

  stage(0, 0);
  __syncthreads();

  for (int t = 0; t < 8; ++t) {
    int cur = t & 1;
    if (t < 7) stage(cur ^ 1, (t + 1) * 32);  // prefetch next tile (other buf)
    bf16x8_t af[4], bfr[4];
#pragma unroll
    for (int i = 0; i < 4; ++i)
      af[i] = *(const bf16x8_t*)(&Al[cur][(wm + i * 16 + mrow) * 32 + grp * 8]);
#pragma unroll
    for (int j = 0; j < 4; ++j)
      bfr[j] = *(const bf16x8_t*)(&Bl[cur][(wn + j * 16 + mrow) * 32 + grp * 8]);
    // operand-swapped: D = (B^T frag) x (A frag)  =>  lane holds row = mrow,
    // cols = grp*4 + reg (4 consecutive columns) -> packed 8B stores
#pragma unroll
    for (int i = 0; i < 4; ++i)
#pragma unroll
      for (int j = 0; j < 4; ++j)
        acc[i][j] = __builtin_amdgcn_mfma_f32_16x16x32_bf16(bfr[j], af[i], acc[i][j], 0, 0, 0);
    __syncthreads();
  }

#pragma unroll
  for (int i = 0; i < 4; ++i) {
    int row = m0 + wm + i * 16 + mrow;
    if (row >= M) continue;
#pragma unroll
    for (int j = 0; j < 4; ++j) {
      u16 pk[4];
      pk[0] = f2bf(acc[i][j][0]);
      pk[1] = f2bf(acc[i][j][1]);
      pk[2] = f2bf(acc[i][j][2]);
      pk[3] = f2bf(acc[i][j][3]);
      *(uint2*)(C + (size_t)row * NF + n0 + wn + j * 16 + grp * 4) = *(const uint2*)pk;
    }
  }
}

// ---- aggregation from packed records; 16B/lane gathers, half-split wave ----
__global__ __launch_bounds__(256) void agg_pack(
    const u16* __restrict__ sup, const int* __restrict__ offs,
    const uint2* __restrict__ rec,
    const u16* __restrict__ bbf, u16* __restrict__ out2, float* __restrict__ out4,
    const int* __restrict__ flagp, int outmask) {
  int node = blockIdx.x * 4 + (threadIdx.x >> 6);
  int lane = threadIdx.x & 63;
  int half = lane >> 5;
  int c0 = (lane & 31) * 8;  // 8 bf16 cols per lane; 32 lanes cover the row
  float a0 = 0.f, a1 = 0.f, a2 = 0.f, a3 = 0.f, a4 = 0.f, a5 = 0.f, a6 = 0.f, a7 = 0.f;
  int eend = offs[node + 1];
  int e = offs[node] + half;  // half 0: even slots, half 1: odd slots

  for (; e + 6 < eend; e += 8) {
    uint2 r0 = rec[e], r1 = rec[e + 2], r2 = rec[e + 4], r3 = rec[e + 6];
    float w0 = u2f(r0.y), w1 = u2f(r1.y), w2 = u2f(r2.y), w3 = u2f(r3.y);
    U8 v0, v1, v2, v3;
    v0.q = *(const uint4*)(sup + (((u32)r0.x) << 8) + c0);
    v1.q = *(const uint4*)(sup + (((u32)r1.x) << 8) + c0);
    v2.q = *(const uint4*)(sup + (((u32)r2.x) << 8) + c0);
    v3.q = *(const uint4*)(sup + (((u32)r3.x) << 8) + c0);
    a0 += bf2f(v0.s[0]) * w0; a1 += bf2f(v0.s[1]) * w0; a2 += bf2f(v0.s[2]) * w0; a3 += bf2f(v0.s[3]) * w0;
    a4 += bf2f(v0.s[4]) * w0; a5 += bf2f(v0.s[5]) * w0; a6 += bf2f(v0.s[6]) * w0; a7 += bf2f(v0.s[7]) * w0;
    a0 += bf2f(v1.s[0]) * w1; a1 += bf2f(v1.s[1]) * w1; a2 += bf2f(v1.s[2]) * w1; a3 += bf2f(v1.s[3]) * w1;
    a4 += bf2f(v1.s[4]) * w1; a5 += bf2f(v1.s[5]) * w1; a6 += bf2f(v1.s[6]) * w1; a7 += bf2f(v1.s[7]) * w1;
    a0 += bf2f(v2.s[0]) * w2; a1 += bf2f(v2.s[1]) * w2; a2 += bf2f(v2.s[2]) * w2; a3 += bf2f(v2.s[3]) * w2;
    a4 += bf2f(v2.s[4]) * w2; a5 += bf2f(v2.s[5]) * w2; a6 += bf2f(v2.s[6]) * w2; a7 += bf2f(v2.s[7]) * w2;
    a0 += bf2f(v3.s[0]) * w3; a1 += bf2f(v3.s[1]) * w3; a2 += bf2f(v3.s[2]) * w3; a3 += bf2f(v3.s[3]) * w3;
    a4 += bf2f(v3.s[4]) * w3; a5 += bf2f(v3.s[5]) * w3; a6 += bf2f(v3.s[6]) * w3; a7 += bf2f(v3.s[7]) * w3;
  }
  for (; e < eend; e += 2) {
    uint2 r0 = rec[e];
    float w0 = u2f(r0.y);
    U8 v0;
    v0.q = *(const uint4*)(sup + (((u32)r0.x) << 8) + c0);
    a0 += bf2f(v0.s[0]) * w0; a1 += bf2f(v0.s[1]) * w0; a2 += bf2f(v0.s[2]) * w0; a3 += bf2f(v0.s[3]) * w0;
    a4 += bf2f(v0.s[4]) * w0; a5 += bf2f(v0.s[5]) * w0; a6 += bf2f(v0.s[6]) * w0; a7 += bf2f(v0.s[7]) * w0;
  }

  // combine the two half-wave partial sums
  a0 += __shfl_xor(a0, 32); a1 += __shfl_xor(a1, 32);
  a2 += __shfl_xor(a2, 32); a3 += __shfl_xor(a3, 32);
  a4 += __shfl_xor(a4, 32); a5 += __shfl_xor(a5, 32);
  a6 += __shfl_xor(a6, 32); a7 += __shfl_xor(a7, 32);

  if (half == 0) {
    U8 bv; bv.q = *(const uint4*)(bbf + c0);
    float r0 = a0 + bf2f(bv.s[0]);
    float r1 = a1 + bf2f(bv.s[1]);
    float r2 = a2 + bf2f(bv.s[2]);
    float r3 = a3 + bf2f(bv.s[3]);
    float r4 = a4 + bf2f(bv.s[4]);
    float r5 = a5 + bf2f(bv.s[5]);
    float r6 = a6 + bf2f(bv.s[6]);
    float r7 = a7 + bf2f(bv.s[7]);
    r0 = r0 > 0.f ? r0 : expm1f(r0);
    r1 = r1 > 0.f ? r1 : expm1f(r1);
    r2 = r2 > 0.f ? r2 : expm1f(r2);
    r3 = r3 > 0.f ? r3 : expm1f(r3);
    r4 = r4 > 0.f ? r4 : expm1f(r4);
    r5 = r5 > 0.f ? r5 : expm1f(r5);
    r6 = r6 > 0.f ? r6 : expm1f(r6);
    r7 = r7 > 0.f ? r7 : expm1f(r7);
    if (outmask && flagp[0]) {
      float4 o4a, o4b;
      o4a.x = r0; o4a.y = r1; o4a.z = r2; o4a.w = r3;
      o4b.x = r4; o4b.y = r5; o4b.z = r6; o4b.w = r7;
      *(float4*)(out4 + (size_t)node * NF + c0) = o4a;
      *(float4*)(out4 + (size_t)node * NF + c0 + 4) = o4b;
    } else {
      U8 o;
      o.s[0] = f2bf(r0); o.s[1] = f2bf(r1); o.s[2] = f2bf(r2); o.s[3] = f2bf(r3);
      o.s[4] = f2bf(r4); o.s[5] = f2bf(r5); o.s[6] = f2bf(r6); o.s[7] = f2bf(r7);
      *(uint4*)(out2 + (size_t)node * NF + c0) = o.q;
    }
  }
}

// ---- split-stream aggregation (fallback) ----
__global__ __launch_bounds__(256) void agg_full(
    const u16* __restrict__ sup, const int* __restrict__ offs,
    const int* __restrict__ ssrc, const u16* __restrict__ sw,
    const u16* __restrict__ bbf, u16* __restrict__ out2, float* __restrict__ out4,
    const int* __restrict__ flagp, int outmask) {
  int node = blockIdx.x * 4 + (threadIdx.x >> 6);
  int lane = threadIdx.x & 63;
  int half = lane >> 5;
  int c0 = (lane & 31) * 8;
  float a0 = 0.f, a1 = 0.f, a2 = 0.f, a3 = 0.f, a4 = 0.f, a5 = 0.f, a6 = 0.f, a7 = 0.f;
  int eend = offs[node + 1];
  int e = offs[node] + half;

  for (; e + 6 < eend; e += 8) {
    int s0 = ssrc[e], s1 = ssrc[e + 2], s2 = ssrc[e + 4], s3 = ssrc[e + 6];
    float w0 = bf2f(sw[e]), w1 = bf2f(sw[e + 2]), w2 = bf2f(sw[e + 4]), w3 = bf2f(sw[e + 6]);
    U8 v0, v1, v2, v3;
    v0.q = *(const uint4*)(sup + (((u32)s0) << 8) + c0);
    v1.q = *(const uint4*)(sup + (((u32)s1) << 8) + c0);
    v2.q = *(const uint4*)(sup + (((u32)s2) << 8) + c0);
    v3.q = *(const uint4*)(sup + (((u32)s3) << 8) + c0);
    a0 += bf2f(v0.s[0]) * w0; a1 += bf2f(v0.s[1]) * w0; a2 += bf2f(v0.s[2]) * w0; a3 += bf2f(v0.s[3]) * w0;
    a4 += bf2f(v0.s[4]) * w0; a5 += bf2f(v0.s[5]) * w0; a6 += bf2f(v0.s[6]) * w0; a7 += bf2f(v0.s[7]) * w0;
    a0 += bf2f(v1.s[0]) * w1; a1 += bf2f(v1.s[1]) * w1; a2 += bf2f(v1.s[2]) * w1; a3 += bf2f(v1.s[3]) * w1;
    a4 += bf2f(v1.s[4]) * w1; a5 += bf2f(v1.s[5]) * w1; a6 += bf2f(v1.s[6]) * w1; a7 += bf2f(v1.s[7]) * w1;
    a0 += bf2f(v2.s[0]) * w2; a1 += bf2f(v2.s[1]) * w2; a2 += bf2f(v2.s[2]) * w2; a3 += bf2f(v2.s[3]) * w2;
    a4 += bf2f(v2.s[4]) * w2; a5 += bf2f(v2.s[5]) * w2; a6 += bf2f(v2.s[6]) * w2; a7 += bf2f(v2.s[7]) * w2;
    a0 += bf2f(v3.s[0]) * w3; a1 += bf2f(v3.s[1]) * w3; a2 += bf2f(v3.s[2]) * w3; a3 += bf2f(v3.s[3]) * w3;
    a4 += bf2f(v3.s[4]) * w3; a5 += bf2f(v3.s[5]) * w3; a6 += bf2f(v3.s[6]) * w3; a7 += bf2f(v3.s[7]) * w3;
  }
  for (; e < eend; e += 2) {
    int s0 = ssrc[e];
    float w0 = bf2f(sw[e]);
    U8 v0;
    v0.q = *(const uint4*)(sup + (((u32)s0) << 8) + c0);
    a0 += bf2f(v0.s[0]) * w0; a1 += bf2f(v0.s[1]) * w0; a2 += bf2f(v0.s[2]) * w0; a3 += bf2f(v0.s[3]) * w0;
    a4 += bf2f(v0.s[4]) * w0; a5 += bf2f(v0.s[5]) * w0; a6 += bf2f(v0.s[6]) * w0; a7 += bf2f(v0.s[7]) * w0;
  }

  a0 += __shfl_xor(a0, 32); a1 += __shfl_xor(a1, 32);
  a2 += __shfl_xor(a2, 32); a3 += __shfl_xor(a3, 32);
  a4 += __shfl_xor(a4, 32); a5 += __shfl_xor(a5, 32);
  a6 += __shfl_xor(a6, 32); a7 += __shfl_xor(a7, 32);

  if (half == 0) {
    U8 bv; bv.q = *(const uint4*)(bbf + c0);
    float r0 = a0 + bf2f(bv.s[0]);
    float r1 = a1 + bf2f(bv.s[1]);
    float r2 = a2 + bf2f(bv.s[2]);
    float r3 = a3 + bf2f(bv.s[3]);
    float r4 = a4 + bf2f(bv.s[4]);
    float r5 = a5 + bf2f(bv.s[5]);
    float r6 = a6 + bf2f(bv.s[6]);
    float r7 = a7 + bf2f(bv.s[7]);
    r0 = r0 > 0.f ? r0 : expm1f(r0);
    r1 = r1 > 0.f ? r1 : expm1f(r1);
    r2 = r2 > 0.f ? r2 : expm1f(r2);
    r3 = r3 > 0.f ? r3 : expm1f(r3);
    r4 = r4 > 0.f ? r4 : expm1f(r4);
    r5 = r5 > 0.f ? r5 : expm1f(r5);
    r6 = r6 > 0.f ? r6 : expm1f(r6);
    r7 = r7 > 0.f ? r7 : expm1f(r7);
    if (outmask && flagp[0]) {
      float4 o4a, o4b;
      o4a.x = r0; o4a.y = r1; o4a.z = r2; o4a.w = r3;
      o4b.x = r4; o4b.y = r5; o4b.z = r6; o4b.w = r7;
      *(float4*)(out4 + (size_t)node * NF + c0) = o4a;
      *(float4*)(out4 + (size_t)node * NF + c0 + 4) = o4b;
    } else {
      U8 o;
      o.s[0] = f2bf(r0); o.s[1] = f2bf(r1); o.s[2] = f2bf(r2); o.s[3] = f2bf(r3);
      o.s[4] = f2bf(r4); o.s[5] = f2bf(r5); o.s[6] = f2bf(r6); o.s[7] = f2bf(r7);
      *(uint4*)(out2 + (size_t)node * NF + c0) = o.q;
    }
  }
}

// ---- compact variant: sorted edge-id, indirect to esrc/ew (small-ws fallback) ----
__global__ __launch_bounds__(256) void agg_eid(
    const u16* __restrict__ sup, const int* __restrict__ offs,
    const int* __restrict__ seid, const int* __restrict__ esrc,
    const u16* __restrict__ ewu, const float* __restrict__ ewf,
    const u16* __restrict__ bbf, u16* __restrict__ out2, float* __restrict__ out4,
    const int* __restrict__ flagp, int outmask) {
  int node = blockIdx.x * 4 + (threadIdx.x >> 6);
  int lane = threadIdx.x & 63;
  int c0 = lane * 4;
  int isf = flagp[0];
  float a0 = 0.f, a1 = 0.f, a2 = 0.f, a3 = 0.f;
  int e = offs[node];
  int eend = offs[node + 1];
  for (; e < eend; ++e) {
    int eid = seid[e];
    int src = esrc[eid];
    float w = isf ? ewf[eid] : bf2f(ewu[eid]);
    ushort4 v = *(const ushort4*)(sup + (size_t)src * NF + c0);
    a0 += bf2f(v.x) * w;
    a1 += bf2f(v.y) * w;
    a2 += bf2f(v.z) * w;
    a3 += bf2f(v.w) * w;
  }
  ushort4 bv = *(const ushort4*)(bbf + c0);
  float r0 = a0 + bf2f(bv.x);
  float r1 = a1 + bf2f(bv.y);
  float r2 = a2 + bf2f(bv.z);
  float r3 = a3 + bf2f(bv.w);
  r0 = r0 > 0.f ? r0 : expm1f(r0);
  r1 = r1 > 0.f ? r1 : expm1f(r1);
  r2 = r2 > 0.f ? r2 : expm1f(r2);
  r3 = r3 > 0.f ? r3 : expm1f(r3);
  if (outmask && isf) {
    float4 o4;
    o4.x = r0; o4.y = r1; o4.z = r2; o4.w = r3;
    *(float4*)(out4 + (size_t)node * NF + c0) = o4;
  } else {
    ushort4 o;
    o.x = f2bf(r0); o.y = f2bf(r1); o.z = f2bf(r2); o.w = f2bf(r3);
    *(ushort4*)(out2 + (size_t)node * NF + c0) = o;
  }
}

extern "C" void kernel_launch(void* const* d_in, const int* in_sizes, int n_in,
                              void* d_out, int out_size, void* d_ws, size_t ws_size,
                              hipStream_t stream) {
  const u16* x2    = (const u16*)d_in[0];
  const float* x4  = (const float*)d_in[0];
  const u16* W1u   = (const u16*)d_in[1];
  const float* W1f = (const float*)d_in[1];
  const u16* b1u   = (const u16*)d_in[2];
  const float* b1f = (const float*)d_in[2];
  const u16* W2u   = (const u16*)d_in[3];
  const float* W2f = (const float*)d_in[3];
  const u16* b2u   = (const u16*)d_in[4];
  const float* b2f = (const float*)d_in[4];
  const u16* ewu   = (const u16*)d_in[5];
  const float* ewf = (const float*)d_in[5];
  const int* esrc  = (const int*)d_in[6];
  const int* edst  = (const int*)d_in[7];
  u16* out2  = (u16*)d_out;
  float* out4 = (float*)d_out;

  // explicit workspace layout (all offsets 256B-aligned)
  char* ws = (char*)d_ws;
  size_t oWt1     = 0;                      // 131072
  size_t oWt2     = 131072;                 // 131072
  size_t oSup     = 262144;                 // 51,200,000 (also hosts rank[] pre-GEMM1)
  size_t oCounts  = 51462144;               // 400,384
  size_t oOffs    = 51862528;               // 400,384
  size_t oPartial = 52663296;               // 2048
  size_t oFlag    = 52665344;               // 256
  size_t oBb1     = 52665600;               // 1024
  size_t oBb2     = 52666624;               // 1024
  size_t oTail    = 52667648;
  size_t need_pack  = oTail + (size_t)N_EDGES * 8;            // packed records
  size_t need_split = oTail + 12800000 + 6400000;             // ssrc + sw

  u16* Wt1     = (u16*)(ws + oWt1);
  u16* Wt2     = (u16*)(ws + oWt2);
  u16* sup     = (u16*)(ws + oSup);
  int* rank    = (int*)(ws + oSup);   // dead before gemm1 writes sup
  int* counts  = (int*)(ws + oCounts);
  int* offs    = (int*)(ws + oOffs);
  int* partial = (int*)(ws + oPartial);
  int* flag    = (int*)(ws + oFlag);
  u16* bb1     = (u16*)(ws + oBb1);
  u16* bb2     = (u16*)(ws + oBb2);

  // d_out doubles as scratch: lower half = h1 (layer-1 bf16 activation),
  // upper half = xbf (bf16-converted x; dead after gemm1; only used when flag=1,
  // in which case d_out is the 102.4MB f32 buffer so the upper half exists).
  u16* h1  = out2;
  u16* xbf = (u16*)((char*)d_out + (size_t)N_NODES * NF * 2);

  sniff_kernel<<<1, 256, 0, stream>>>(x2, flag);
  hipMemsetAsync(counts, 0, (size_t)N_NODES * 4, stream);
  prep_all<<<25514, 256, 0, stream>>>(edst, counts, rank, x4, xbf,
                                      W1u, W1f, W2u, W2f, b1u, b1f, b2u, b2f,
                                      flag, Wt1, Wt2, bb1, bb2);
  scanA<<<391, 256, 0, stream>>>(counts, partial);
  scanB<<<1, 512, 0, stream>>>(partial);
  scanC<<<391, 256, 0, stream>>>(counts, partial, offs);

  dim3 ggrid((N_NODES + 127) / 128, 2);

  if (ws_size >= need_pack) {
    uint2* rec = (uint2*)(ws + oTail);
    place_pack<<<N_EDGES / 256, 256, 0, stream>>>(esrc, edst, ewu, ewf, flag, offs, rank, rec);
    gemm_gll<<<ggrid, 256, 0, stream>>>(x2, xbf, Wt1, sup, N_NODES, flag);
    agg_pack<<<N_NODES / 4, 256, 0, stream>>>(sup, offs, rec, bb1, h1, out4, flag, 0);
    gemm_gll<<<ggrid, 256, 0, stream>>>(h1, h1, Wt2, sup, N_NODES, flag);
    agg_pack<<<N_NODES / 4, 256, 0, stream>>>(sup, offs, rec, bb2, out2, out4, flag, 1);
  } else if (ws_size >= need_split) {
    int* ssrc = (int*)(ws + oTail);
    u16* sw   = (u16*)(ws + oTail + 12800000);
    place_full<<<N_EDGES / 256, 256, 0, stream>>>(esrc, edst, ewu, ewf, flag, offs, rank, ssrc, sw);
    gemm_gll<<<ggrid, 256, 0, stream>>>(x2, xbf, Wt1, sup, N_NODES, flag);
    agg_full<<<N_NODES / 4, 256, 0, stream>>>(sup, offs, ssrc, sw, bb1, h1, out4, flag, 0);
    gemm_gll<<<ggrid, 256, 0, stream>>>(h1, h1, Wt2, sup, N_NODES, flag);
    agg_full<<<N_NODES / 4, 256, 0, stream>>>(sup, offs, ssrc, sw, bb2, out2, out4, flag, 1);
  } else {
    int* seid = (int*)(ws + oTail);
    place_eid<<<N_EDGES / 256, 256, 0, stream>>>(edst, offs, rank, seid);
    gemm_gll<<<ggrid, 256, 0, stream>>>(x2, xbf, Wt1, sup, N_NODES, flag);
    agg_eid<<<N_NODES / 4, 256, 0, stream>>>(sup, offs, seid, esrc, ewu, ewf, bb1, h1, out4, flag, 0);
    gemm_gll<<<ggrid, 256, 0, stream>>>(h1, h1, Wt2, sup, N_NODES, flag);
    agg_eid<<<N_NODES / 4, 256, 0, stream>>>(sup, offs, seid, esrc, ewu, ewf, bb2, out2, out4, flag, 1);
  }
}

// Round 8
// 966.024 us; speedup vs baseline: 1.0855x; 1.0054x over previous
//
#include <hip/hip_runtime.h>
#include <math.h>

#define N_NODES 100000
#define N_EDGES 3200000
#define NF 256

typedef unsigned short u16;
typedef unsigned int u32;

typedef __bf16 bf16x8_t __attribute__((ext_vector_type(8)));
typedef float f32x4_t __attribute__((ext_vector_type(4)));

union U8 { uint4 q; u16 s[8]; };

typedef __attribute__((address_space(1))) const void* as1_cvp;
typedef __attribute__((address_space(3))) void* as3_vp;

__device__ __forceinline__ float bf2f(u16 u) {
  union { u32 i; float f; } v; v.i = ((u32)u) << 16; return v.f;
}
__device__ __forceinline__ u16 f2bf(float f) {
  union { float f; u32 i; } v; v.f = f;
  u32 x = v.i;
  u32 r = (x + 0x7FFFu + ((x >> 16) & 1u)) >> 16;
  return (u16)r;
}
__device__ __forceinline__ float u2f(u32 u) {
  union { u32 i; float f; } v; v.i = u; return v.f;
}

__device__ __forceinline__ void gload_lds16(const u16* g, u16* l) {
  __builtin_amdgcn_global_load_lds((as1_cvp)g, (as3_vp)l, 16, 0, 0);
}

// ---- dtype sniff: bf16-NaN bit patterns appear in f32 mantissa halves only ----
__global__ void sniff_kernel(const u16* __restrict__ xr, int* __restrict__ flag) {
  __shared__ int cnt;
  if (threadIdx.x == 0) cnt = 0;
  __syncthreads();
  int c = 0;
  for (int i = threadIdx.x; i < 65536; i += 256) {
    u16 u = xr[i];
    if ((u & 0x7F80u) == 0x7F80u) c++;
  }
  atomicAdd(&cnt, c);
  __syncthreads();
  if (threadIdx.x == 0) flag[0] = (cnt >= 4) ? 1 : 0;  // 1 => inputs are f32
}

// ---- fused prep: hist_rank (12500 blk) + conv_x (12500 blk) + W/b prep (514 blk) ----
__global__ void prep_all(const int* __restrict__ dst, int* __restrict__ counts,
                         int* __restrict__ rank,
                         const float* __restrict__ xf, u16* __restrict__ xbf,
                         const u16* __restrict__ W1u, const float* __restrict__ W1f,
                         const u16* __restrict__ W2u, const float* __restrict__ W2f,
                         const u16* __restrict__ b1u, const float* __restrict__ b1f,
                         const u16* __restrict__ b2u, const float* __restrict__ b2f,
                         const int* __restrict__ flagp,
                         u16* __restrict__ Wt1, u16* __restrict__ Wt2,
                         u16* __restrict__ bb1, u16* __restrict__ bb2) {
  int b = blockIdx.x;
  int t = threadIdx.x;
  if (b < 12500) {
    // hist_rank
    int e = b * 256 + t;
    rank[e] = atomicAdd(&counts[dst[e]], 1);
  } else if (b < 25000) {
    // conv_x: 8 elems/thread
    if (!flagp[0]) return;
    size_t i = ((size_t)(b - 12500) * 256 + t) * 8;
    float4 a = *(const float4*)(xf + i);
    float4 c = *(const float4*)(xf + i + 4);
    U8 o;
    o.s[0] = f2bf(a.x); o.s[1] = f2bf(a.y); o.s[2] = f2bf(a.z); o.s[3] = f2bf(a.w);
    o.s[4] = f2bf(c.x); o.s[5] = f2bf(c.y); o.s[6] = f2bf(c.z); o.s[7] = f2bf(c.w);
    *(uint4*)(xbf + i) = o.q;
  } else {
    int pb = b - 25000;
    int isf = flagp[0];
    if (pb < 256) {
      Wt1[t * NF + pb] = isf ? f2bf(W1f[pb * NF + t]) : W1u[pb * NF + t];
    } else if (pb < 512) {
      int k = pb - 256;
      Wt2[t * NF + k] = isf ? f2bf(W2f[k * NF + t]) : W2u[k * NF + t];
    } else if (pb == 512) {
      bb1[t] = isf ? f2bf(b1f[t]) : b1u[t];
    } else {
      bb2[t] = isf ? f2bf(b2f[t]) : b2u[t];
    }
  }
}

__global__ void scanA(const int* __restrict__ counts, int* __restrict__ partial) {
  __shared__ int s[256];
  int t = threadIdx.x;
  int gid = blockIdx.x * 256 + t;
  int v = (gid < N_NODES) ? counts[gid] : 0;
  s[t] = v;
  __syncthreads();
  for (int offd = 128; offd > 0; offd >>= 1) {
    if (t < offd) s[t] += s[t + offd];
    __syncthreads();
  }
  if (t == 0) partial[blockIdx.x] = s[0];
}

__global__ void scanB(int* __restrict__ partial) {
  const int NPART = 391;
  __shared__ int s[512];
  int t = threadIdx.x;
  int v = (t < NPART) ? partial[t] : 0;
  s[t] = v;
  __syncthreads();
  for (int offd = 1; offd < 512; offd <<= 1) {
    int x = 0;
    if (t >= offd) x = s[t - offd];
    __syncthreads();
    s[t] += x;
    __syncthreads();
  }
  if (t < NPART) partial[t] = (t == 0) ? 0 : s[t - 1];  // exclusive
}

__global__ void scanC(const int* __restrict__ counts, const int* __restrict__ partial,
                      int* __restrict__ offs) {
  __shared__ int s[256];
  int t = threadIdx.x;
  int b = blockIdx.x;
  int gid = b * 256 + t;
  int v = (gid < N_NODES) ? counts[gid] : 0;
  s[t] = v;
  __syncthreads();
  for (int offd = 1; offd < 256; offd <<= 1) {
    int x = 0;
    if (t >= offd) x = s[t - offd];
    __syncthreads();
    s[t] += x;
    __syncthreads();
  }
  int incl = s[t];
  if (gid < N_NODES) offs[gid] = partial[b] + (incl - v);
  if (gid == N_NODES - 1) offs[N_NODES] = partial[b] + incl;
}

// ---- fused GEMM1 + packed placement, 1:8 modular interleave for co-residency ----
// bx % 9 == 0 -> GEMM block (gi = bx/9, 1564 of them); else scatter block.
#define GEMM_CNT 1564
#define FUSE_GRID 14068  // smallest T with 1564 multiples of 9 and >= 12500 others

__global__ __launch_bounds__(256) void gemm1_place(
    const u16* __restrict__ A0, const u16* __restrict__ A1,
    const u16* __restrict__ Bt, u16* __restrict__ C, int M,
    const int* __restrict__ flagp,
    const int* __restrict__ src, const int* __restrict__ dst,
    const u16* __restrict__ wu, const float* __restrict__ wf,
    const int* __restrict__ offs, const int* __restrict__ rank,
    uint2* __restrict__ rec) {
  __shared__ __align__(16) u16 Al[2][128 * 32];
  __shared__ __align__(16) u16 Bl[2][128 * 32];
  const int bx = blockIdx.x;
  const int tid = threadIdx.x;

  if (bx % 9 != 0) {
    // ---- scatter role ----
    int pidx = bx - (bx / 9 + 1);      // index among non-multiple-of-9 blocks
    if (pidx >= 12500) return;
    int e = pidx * 256 + tid;
    int pos = offs[dst[e]] + rank[e];
    float w = flagp[0] ? wf[e] : bf2f(wu[e]);
    uint2 r;
    r.x = (u32)src[e];
    r.y = __float_as_uint(w);
    rec[pos] = r;
    return;
  }

  // ---- GEMM role ----
  const int gi = bx / 9;               // 0..1563
  const u16* A = flagp[0] ? A1 : A0;
  const int m0 = (gi >> 1) * 128;
  const int n0 = (gi & 1) * 128;
  const int lane = tid & 63;
  const int wave = tid >> 6;
  const int wm = (wave & 1) * 64;
  const int wn = (wave >> 1) * 64;
  const int mrow = lane & 15;
  const int grp = lane >> 4;

  f32x4_t acc[4][4];
  const f32x4_t zero = {0.f, 0.f, 0.f, 0.f};
#pragma unroll
  for (int i = 0; i < 4; ++i)
#pragma unroll
    for (int j = 0; j < 4; ++j) acc[i][j] = zero;

  const int rA = lane >> 2;
  const int cA = (lane & 3) * 8;
  const int r0 = wave * 32;

  auto stage = [&](int buf, int k0) {
#pragma unroll
    for (int c = 0; c < 2; ++c) {
      int rr = r0 + c * 16;
      int ar = rr + rA;
      int gm = m0 + ar;
      if (gm >= M) gm = 0;
      gload_lds16(A + (size_t)gm * NF + k0 + cA, &Al[buf][rr * 32]);
      gload_lds16(Bt + (size_t)(n0 + ar) * NF + k0 + cA, &Bl[buf][rr * 32]);
    }
  };

  stage(0, 0);
  __syncthreads();

  for (int t = 0; t < 8; ++t) {
    int cur = t & 1;
    if (t < 7) stage(cur ^ 1, (t + 1) * 32);
    bf16x8_t af[4], bfr[4];
#pragma unroll
    for (int i = 0; i < 4; ++i)
      af[i] = *(const bf16x8_t*)(&Al[cur][(wm + i * 16 + mrow) * 32 + grp * 8]);
#pragma unroll
    for (int j = 0; j < 4; ++j)
      bfr[j] = *(const bf16x8_t*)(&Bl[cur][(wn + j * 16 + mrow) * 32 + grp * 8]);
#pragma unroll
    for (int i = 0; i < 4; ++i)
#pragma unroll
      for (int j = 0; j < 4; ++j)
        acc[i][j] = __builtin_amdgcn_mfma_f32_16x16x32_bf16(bfr[j], af[i], acc[i][j], 0, 0, 0);
    __syncthreads();
  }

#pragma unroll
  for (int i = 0; i < 4; ++i) {
    int row = m0 + wm + i * 16 + mrow;
    if (row >= M) continue;
#pragma unroll
    for (int j = 0; j < 4; ++j) {
      u16 pk[4];
      pk[0] = f2bf(acc[i][j][0]);
      pk[1] = f2bf(acc[i][j][1]);
      pk[2] = f2bf(acc[i][j][2]);
      pk[3] = f2bf(acc[i][j][3]);
      *(uint2*)(C + (size_t)row * NF + n0 + wn + j * 16 + grp * 4) = *(const uint2*)pk;
    }
  }
}

// ---- split placement (fallback when ws too small for packed) ----
__global__ void place_full(const int* __restrict__ src, const int* __restrict__ dst,
                           const u16* __restrict__ wu, const float* __restrict__ wf,
                           const int* __restrict__ flagp, const int* __restrict__ offs,
                           const int* __restrict__ rank,
                           int* __restrict__ ssrc, u16* __restrict__ sw) {
  int e = blockIdx.x * 256 + threadIdx.x;
  int pos = offs[dst[e]] + rank[e];
  ssrc[pos] = src[e];
  if (flagp[0]) sw[pos] = f2bf(wf[e]);
  else          sw[pos] = wu[e];
}

__global__ void place_eid(const int* __restrict__ dst, const int* __restrict__ offs,
                          const int* __restrict__ rank, int* __restrict__ seid) {
  int e = blockIdx.x * 256 + threadIdx.x;
  seid[offs[dst[e]] + rank[e]] = e;
}

// ---- bf16 MFMA GEMM: global_load_lds staging, 2-phase double-buffer ----
__global__ __launch_bounds__(256) void gemm_gll(
    const u16* __restrict__ A0, const u16* __restrict__ A1,
    const u16* __restrict__ Bt, u16* __restrict__ C, int M,
    const int* __restrict__ flagp) {
  __shared__ __align__(16) u16 Al[2][128 * 32];
  __shared__ __align__(16) u16 Bl[2][128 * 32];
  const u16* A = flagp[0] ? A1 : A0;
  const int tid = threadIdx.x;
  const int m0 = blockIdx.x * 128;
  const int n0 = blockIdx.y * 128;
  const int lane = tid & 63;
  const int wave = tid >> 6;
  const int wm = (wave & 1) * 64;
  const int wn = (wave >> 1) * 64;
  const int mrow = lane & 15;
  const int grp = lane >> 4;

  f32x4_t acc[4][4];
  const f32x4_t zero = {0.f, 0.f, 0.f, 0.f};
#pragma unroll
  for (int i = 0; i < 4; ++i)
#pragma unroll
    for (int j = 0; j < 4; ++j) acc[i][j] = zero;

  const int rA = lane >> 2;
  const int cA = (lane & 3) * 8;
  const int r0 = wave * 32;

  auto stage = [&](int buf, int k0) {
#pragma unroll
    for (int c = 0; c < 2; ++c) {
      int rr = r0 + c * 16;
      int ar = rr + rA;
      int gm = m0 + ar;
      if (gm >= M) gm = 0;
      gload_lds16(A + (size_t)gm * NF + k0 + cA, &Al[buf][rr * 32]);
      gload_lds16(Bt + (size_t)(n0 + ar) * NF + k0 + cA, &Bl[buf][rr * 32]);
    }
  };

  stage(0, 0);
  __syncthreads();

  for (int t = 0; t < 8; ++t) {
    int cur = t & 1;
    if (t < 7) stage(cur ^ 1, (t + 1) * 32);
    bf16x8_t af[4], bfr[4];
#pragma unroll
    for (int i = 0; i < 4; ++i)
      af[i] = *(const bf16x8_t*)(&Al[cur][(wm + i * 16 + mrow) * 32 + grp * 8]);
#pragma unroll
    for (int j = 0; j < 4; ++j)
      bfr[j] = *(const bf16x8_t*)(&Bl[cur][(wn + j * 16 + mrow) * 32 + grp * 8]);
#pragma unroll
    for (int i = 0; i < 4; ++i)
#pragma unroll
      for (int j = 0; j < 4; ++j)
        acc[i][j] = __builtin_amdgcn_mfma_f32_16x16x32_bf16(bfr[j], af[i], acc[i][j], 0, 0, 0);
    __syncthreads();
  }

#pragma unroll
  for (int i = 0; i < 4; ++i) {
    int row = m0 + wm + i * 16 + mrow;
    if (row >= M) continue;
#pragma unroll
    for (int j = 0; j < 4; ++j) {
      u16 pk[4];
      pk[0] = f2bf(acc[i][j][0]);
      pk[1] = f2bf(acc[i][j][1]);
      pk[2] = f2bf(acc[i][j][2]);
      pk[3] = f2bf(acc[i][j][3]);
      *(uint2*)(C + (size_t)row * NF + n0 + wn + j * 16 + grp * 4) = *(const uint2*)pk;
    }
  }
}

// ---- aggregation from packed records; 16B/lane gathers, half-split wave ----
__global__ __launch_bounds__(256) void agg_pack(
    const u16* __restrict__ sup, const int* __restrict__ offs,
    const uint2* __restrict__ rec,
    const u16* __restrict__ bbf, u16* __restrict__ out2, float* __restrict__ out4,
    const int* __restrict__ flagp, int outmask) {
  int node = blockIdx.x * 4 + (threadIdx.x >> 6);
  int lane = threadIdx.x & 63;
  int half = lane >> 5;
  int c0 = (lane & 31) * 8;  // 8 bf16 cols per lane; 32 lanes cover the row
  float a0 = 0.f, a1 = 0.f, a2 = 0.f, a3 = 0.f, a4 = 0.f, a5 = 0.f, a6 = 0.f, a7 = 0.f;
  int eend = offs[node + 1];
  int e = offs[node] + half;  // half 0: even slots, half 1: odd slots

  for (; e + 6 < eend; e += 8) {
    uint2 r0 = rec[e], r1 = rec[e + 2], r2 = rec[e + 4], r3 = rec[e + 6];
    float w0 = u2f(r0.y), w1 = u2f(r1.y), w2 = u2f(r2.y), w3 = u2f(r3.y);
    U8 v0, v1, v2, v3;
    v0.q = *(const uint4*)(sup + (((u32)r0.x) << 8) + c0);
    v1.q = *(const uint4*)(sup + (((u32)r1.x) << 8) + c0);
    v2.q = *(const uint4*)(sup + (((u32)r2.x) << 8) + c0);
    v3.q = *(const uint4*)(sup + (((u32)r3.x) << 8) + c0);
    a0 += bf2f(v0.s[0]) * w0; a1 += bf2f(v0.s[1]) * w0; a2 += bf2f(v0.s[2]) * w0; a3 += bf2f(v0.s[3]) * w0;
    a4 += bf2f(v0.s[4]) * w0; a5 += bf2f(v0.s[5]) * w0; a6 += bf2f(v0.s[6]) * w0; a7 += bf2f(v0.s[7]) * w0;
    a0 += bf2f(v1.s[0]) * w1; a1 += bf2f(v1.s[1]) * w1; a2 += bf2f(v1.s[2]) * w1; a3 += bf2f(v1.s[3]) * w1;
    a4 += bf2f(v1.s[4]) * w1; a5 += bf2f(v1.s[5]) * w1; a6 += bf2f(v1.s[6]) * w1; a7 += bf2f(v1.s[7]) * w1;
    a0 += bf2f(v2.s[0]) * w2; a1 += bf2f(v2.s[1]) * w2; a2 += bf2f(v2.s[2]) * w2; a3 += bf2f(v2.s[3]) * w2;
    a4 += bf2f(v2.s[4]) * w2; a5 += bf2f(v2.s[5]) * w2; a6 += bf2f(v2.s[6]) * w2; a7 += bf2f(v2.s[7]) * w2;
    a0 += bf2f(v3.s[0]) * w3; a1 += bf2f(v3.s[1]) * w3; a2 += bf2f(v3.s[2]) * w3; a3 += bf2f(v3.s[3]) * w3;
    a4 += bf2f(v3.s[4]) * w3; a5 += bf2f(v3.s[5]) * w3; a6 += bf2f(v3.s[6]) * w3; a7 += bf2f(v3.s[7]) * w3;
  }
  for (; e < eend; e += 2) {
    uint2 r0 = rec[e];
    float w0 = u2f(r0.y);
    U8 v0;
    v0.q = *(const uint4*)(sup + (((u32)r0.x) << 8) + c0);
    a0 += bf2f(v0.s[0]) * w0; a1 += bf2f(v0.s[1]) * w0; a2 += bf2f(v0.s[2]) * w0; a3 += bf2f(v0.s[3]) * w0;
    a4 += bf2f(v0.s[4]) * w0; a5 += bf2f(v0.s[5]) * w0; a6 += bf2f(v0.s[6]) * w0; a7 += bf2f(v0.s[7]) * w0;
  }

  // combine the two half-wave partial sums
  a0 += __shfl_xor(a0, 32); a1 += __shfl_xor(a1, 32);
  a2 += __shfl_xor(a2, 32); a3 += __shfl_xor(a3, 32);
  a4 += __shfl_xor(a4, 32); a5 += __shfl_xor(a5, 32);
  a6 += __shfl_xor(a6, 32); a7 += __shfl_xor(a7, 32);

  if (half == 0) {
    U8 bv; bv.q = *(const uint4*)(bbf + c0);
    float r0 = a0 + bf2f(bv.s[0]);
    float r1 = a1 + bf2f(bv.s[1]);
    float r2 = a2 + bf2f(bv.s[2]);
    float r3 = a3 + bf2f(bv.s[3]);
    float r4 = a4 + bf2f(bv.s[4]);
    float r5 = a5 + bf2f(bv.s[5]);
    float r6 = a6 + bf2f(bv.s[6]);
    float r7 = a7 + bf2f(bv.s[7]);
    r0 = r0 > 0.f ? r0 : expm1f(r0);
    r1 = r1 > 0.f ? r1 : expm1f(r1);
    r2 = r2 > 0.f ? r2 : expm1f(r2);
    r3 = r3 > 0.f ? r3 : expm1f(r3);
    r4 = r4 > 0.f ? r4 : expm1f(r4);
    r5 = r5 > 0.f ? r5 : expm1f(r5);
    r6 = r6 > 0.f ? r6 : expm1f(r6);
    r7 = r7 > 0.f ? r7 : expm1f(r7);
    if (outmask && flagp[0]) {
      float4 o4a, o4b;
      o4a.x = r0; o4a.y = r1; o4a.z = r2; o4a.w = r3;
      o4b.x = r4; o4b.y = r5; o4b.z = r6; o4b.w = r7;
      *(float4*)(out4 + (size_t)node * NF + c0) = o4a;
      *(float4*)(out4 + (size_t)node * NF + c0 + 4) = o4b;
    } else {
      U8 o;
      o.s[0] = f2bf(r0); o.s[1] = f2bf(r1); o.s[2] = f2bf(r2); o.s[3] = f2bf(r3);
      o.s[4] = f2bf(r4); o.s[5] = f2bf(r5); o.s[6] = f2bf(r6); o.s[7] = f2bf(r7);
      *(uint4*)(out2 + (size_t)node * NF + c0) = o.q;
    }
  }
}

// ---- split-stream aggregation (fallback) ----
__global__ __launch_bounds__(256) void agg_full(
    const u16* __restrict__ sup, const int* __restrict__ offs,
    const int* __restrict__ ssrc, const u16* __restrict__ sw,
    const u16* __restrict__ bbf, u16* __restrict__ out2, float* __restrict__ out4,
    const int* __restrict__ flagp, int outmask) {
  int node = blockIdx.x * 4 + (threadIdx.x >> 6);
  int lane = threadIdx.x & 63;
  int half = lane >> 5;
  int c0 = (lane & 31) * 8;
  float a0 = 0.f, a1 = 0.f, a2 = 0.f, a3 = 0.f, a4 = 0.f, a5 = 0.f, a6 = 0.f, a7 = 0.f;
  int eend = offs[node + 1];
  int e = offs[node] + half;

  for (; e + 6 < eend; e += 8) {
    int s0 = ssrc[e], s1 = ssrc[e + 2], s2 = ssrc[e + 4], s3 = ssrc[e + 6];
    float w0 = bf2f(sw[e]), w1 = bf2f(sw[e + 2]), w2 = bf2f(sw[e + 4]), w3 = bf2f(sw[e + 6]);
    U8 v0, v1, v2, v3;
    v0.q = *(const uint4*)(sup + (((u32)s0) << 8) + c0);
    v1.q = *(const uint4*)(sup + (((u32)s1) << 8) + c0);
    v2.q = *(const uint4*)(sup + (((u32)s2) << 8) + c0);
    v3.q = *(const uint4*)(sup + (((u32)s3) << 8) + c0);
    a0 += bf2f(v0.s[0]) * w0; a1 += bf2f(v0.s[1]) * w0; a2 += bf2f(v0.s[2]) * w0; a3 += bf2f(v0.s[3]) * w0;
    a4 += bf2f(v0.s[4]) * w0; a5 += bf2f(v0.s[5]) * w0; a6 += bf2f(v0.s[6]) * w0; a7 += bf2f(v0.s[7]) * w0;
    a0 += bf2f(v1.s[0]) * w1; a1 += bf2f(v1.s[1]) * w1; a2 += bf2f(v1.s[2]) * w1; a3 += bf2f(v1.s[3]) * w1;
    a4 += bf2f(v1.s[4]) * w1; a5 += bf2f(v1.s[5]) * w1; a6 += bf2f(v1.s[6]) * w1; a7 += bf2f(v1.s[7]) * w1;
    a0 += bf2f(v2.s[0]) * w2; a1 += bf2f(v2.s[1]) * w2; a2 += bf2f(v2.s[2]) * w2; a3 += bf2f(v2.s[3]) * w2;
    a4 += bf2f(v2.s[4]) * w2; a5 += bf2f(v2.s[5]) * w2; a6 += bf2f(v2.s[6]) * w2; a7 += bf2f(v2.s[7]) * w2;
    a0 += bf2f(v3.s[0]) * w3; a1 += bf2f(v3.s[1]) * w3; a2 += bf2f(v3.s[2]) * w3; a3 += bf2f(v3.s[3]) * w3;
    a4 += bf2f(v3.s[4]) * w3; a5 += bf2f(v3.s[5]) * w3; a6 += bf2f(v3.s[6]) * w3; a7 += bf2f(v3.s[7]) * w3;
  }
  for (; e < eend; e += 2) {
    int s0 = ssrc[e];
    float w0 = bf2f(sw[e]);
    U8 v0;
    v0.q = *(const uint4*)(sup + (((u32)s0) << 8) + c0);
    a0 += bf2f(v0.s[0]) * w0; a1 += bf2f(v0.s[1]) * w0; a2 += bf2f(v0.s[2]) * w0; a3 += bf2f(v0.s[3]) * w0;
    a4 += bf2f(v0.s[4]) * w0; a5 += bf2f(v0.s[5]) * w0; a6 += bf2f(v0.s[6]) * w0; a7 += bf2f(v0.s[7]) * w0;
  }

  a0 += __shfl_xor(a0, 32); a1 += __shfl_xor(a1, 32);
  a2 += __shfl_xor(a2, 32); a3 += __shfl_xor(a3, 32);
  a4 += __shfl_xor(a4, 32); a5 += __shfl_xor(a5, 32);
  a6 += __shfl_xor(a6, 32); a7 += __shfl_xor(a7, 32);

  if (half == 0) {
    U8 bv; bv.q = *(const uint4*)(bbf + c0);
    float r0 = a0 + bf2f(bv.s[0]);
    float r1 = a1 + bf2f(bv.s[1]);
    float r2 = a2 + bf2f(bv.s[2]);
    float r3 = a3 + bf2f(bv.s[3]);
    float r4 = a4 + bf2f(bv.s[4]);
    float r5 = a5 + bf2f(bv.s[5]);
    float r6 = a6 + bf2f(bv.s[6]);
    float r7 = a7 + bf2f(bv.s[7]);
    r0 = r0 > 0.f ? r0 : expm1f(r0);
    r1 = r1 > 0.f ? r1 : expm1f(r1);
    r2 = r2 > 0.f ? r2 : expm1f(r2);
    r3 = r3 > 0.f ? r3 : expm1f(r3);
    r4 = r4 > 0.f ? r4 : expm1f(r4);
    r5 = r5 > 0.f ? r5 : expm1f(r5);
    r6 = r6 > 0.f ? r6 : expm1f(r6);
    r7 = r7 > 0.f ? r7 : expm1f(r7);
    if (outmask && flagp[0]) {
      float4 o4a, o4b;
      o4a.x = r0; o4a.y = r1; o4a.z = r2; o4a.w = r3;
      o4b.x = r4; o4b.y = r5; o4b.z = r6; o4b.w = r7;
      *(float4*)(out4 + (size_t)node * NF + c0) = o4a;
      *(float4*)(out4 + (size_t)node * NF + c0 + 4) = o4b;
    } else {
      U8 o;
      o.s[0] = f2bf(r0); o.s[1] = f2bf(r1); o.s[2] = f2bf(r2); o.s[3] = f2bf(r3);
      o.s[4] = f2bf(r4); o.s[5] = f2bf(r5); o.s[6] = f2bf(r6); o.s[7] = f2bf(r7);
      *(uint4*)(out2 + (size_t)node * NF + c0) = o.q;
    }
  }
}

// ---- compact variant: sorted edge-id, indirect to esrc/ew (small-ws fallback) ----
__global__ __launch_bounds__(256) void agg_eid(
    const u16* __restrict__ sup, const int* __restrict__ offs,
    const int* __restrict__ seid, const int* __restrict__ esrc,
    const u16* __restrict__ ewu, const float* __restrict__ ewf,
    const u16* __restrict__ bbf, u16* __restrict__ out2, float* __restrict__ out4,
    const int* __restrict__ flagp, int outmask) {
  int node = blockIdx.x * 4 + (threadIdx.x >> 6);
  int lane = threadIdx.x & 63;
  int c0 = lane * 4;
  int isf = flagp[0];
  float a0 = 0.f, a1 = 0.f, a2 = 0.f, a3 = 0.f;
  int e = offs[node];
  int eend = offs[node + 1];
  for (; e < eend; ++e) {
    int eid = seid[e];
    int src = esrc[eid];
    float w = isf ? ewf[eid] : bf2f(ewu[eid]);
    ushort4 v = *(const ushort4*)(sup + (size_t)src * NF + c0);
    a0 += bf2f(v.x) * w;
    a1 += bf2f(v.y) * w;
    a2 += bf2f(v.z) * w;
    a3 += bf2f(v.w) * w;
  }
  ushort4 bv = *(const ushort4*)(bbf + c0);
  float r0 = a0 + bf2f(bv.x);
  float r1 = a1 + bf2f(bv.y);
  float r2 = a2 + bf2f(bv.z);
  float r3 = a3 + bf2f(bv.w);
  r0 = r0 > 0.f ? r0 : expm1f(r0);
  r1 = r1 > 0.f ? r1 : expm1f(r1);
  r2 = r2 > 0.f ? r2 : expm1f(r2);
  r3 = r3 > 0.f ? r3 : expm1f(r3);
  if (outmask && isf) {
    float4 o4;
    o4.x = r0; o4.y = r1; o4.z = r2; o4.w = r3;
    *(float4*)(out4 + (size_t)node * NF + c0) = o4;
  } else {
    ushort4 o;
    o.x = f2bf(r0); o.y = f2bf(r1); o.z = f2bf(r2); o.w = f2bf(r3);
    *(ushort4*)(out2 + (size_t)node * NF + c0) = o;
  }
}

extern "C" void kernel_launch(void* const* d_in, const int* in_sizes, int n_in,
                              void* d_out, int out_size, void* d_ws, size_t ws_size,
                              hipStream_t stream) {
  const u16* x2    = (const u16*)d_in[0];
  const float* x4  = (const float*)d_in[0];
  const u16* W1u   = (const u16*)d_in[1];
  const float* W1f = (const float*)d_in[1];
  const u16* b1u   = (const u16*)d_in[2];
  const float* b1f = (const float*)d_in[2];
  const u16* W2u   = (const u16*)d_in[3];
  const float* W2f = (const float*)d_in[3];
  const u16* b2u   = (const u16*)d_in[4];
  const float* b2f = (const float*)d_in[4];
  const u16* ewu   = (const u16*)d_in[5];
  const float* ewf = (const float*)d_in[5];
  const int* esrc  = (const int*)d_in[6];
  const int* edst  = (const int*)d_in[7];
  u16* out2  = (u16*)d_out;
  float* out4 = (float*)d_out;

  // explicit workspace layout (all offsets 256B-aligned)
  char* ws = (char*)d_ws;
  size_t oWt1     = 0;                      // 131072
  size_t oWt2     = 131072;                 // 131072
  size_t oSup     = 262144;                 // 51,200,000 (also hosts rank[] pre-GEMM1)
  size_t oCounts  = 51462144;               // 400,384
  size_t oOffs    = 51862528;               // 400,384
  size_t oPartial = 52663296;               // 2048
  size_t oFlag    = 52665344;               // 256
  size_t oBb1     = 52665600;               // 1024
  size_t oBb2     = 52666624;               // 1024
  size_t oTail    = 52667648;
  size_t need_pack  = oTail + (size_t)N_EDGES * 8;            // packed records
  size_t need_split = oTail + 12800000 + 6400000;             // ssrc + sw

  u16* Wt1     = (u16*)(ws + oWt1);
  u16* Wt2     = (u16*)(ws + oWt2);
  u16* sup     = (u16*)(ws + oSup);
  int* rank    = (int*)(ws + oSup);   // NOTE: rank aliases sup; with the fused
                                      // gemm1_place, rank reads and sup writes
                                      // overlap IN TIME but not in SPACE:
                                      // rank[] occupies bytes [oSup, oSup+12.8MB);
                                      // gemm C-writes go to the same region ONLY
                                      // for rows < 25000. See note below: rank is
                                      // relocated to the tail to avoid this.
  int* counts  = (int*)(ws + oCounts);
  int* offs    = (int*)(ws + oOffs);
  int* partial = (int*)(ws + oPartial);
  int* flag    = (int*)(ws + oFlag);
  u16* bb1     = (u16*)(ws + oBb1);
  u16* bb2     = (u16*)(ws + oBb2);

  // With fused gemm1+place, rank must NOT alias sup (both live simultaneously).
  // Place rank after rec in the tail when space allows: rec needs 25.6MB,
  // rank needs 12.8MB -> tail needs 38.4MB.
  size_t need_fused = oTail + (size_t)N_EDGES * 8 + (size_t)N_EDGES * 4;

  // d_out doubles as scratch: lower half = h1 (layer-1 bf16 activation),
  // upper half = xbf (bf16-converted x; dead after gemm1; only used when flag=1,
  // in which case d_out is the 102.4MB f32 buffer so the upper half exists).
  u16* h1  = out2;
  u16* xbf = (u16*)((char*)d_out + (size_t)N_NODES * NF * 2);

  if (ws_size >= need_fused) {
    uint2* rec   = (uint2*)(ws + oTail);
    int* rank_t  = (int*)(ws + oTail + (size_t)N_EDGES * 8);

    sniff_kernel<<<1, 256, 0, stream>>>(x2, flag);
    hipMemsetAsync(counts, 0, (size_t)N_NODES * 4, stream);
    prep_all<<<25514, 256, 0, stream>>>(edst, counts, rank_t, x4, xbf,
                                        W1u, W1f, W2u, W2f, b1u, b1f, b2u, b2f,
                                        flag, Wt1, Wt2, bb1, bb2);
    scanA<<<391, 256, 0, stream>>>(counts, partial);
    scanB<<<1, 512, 0, stream>>>(partial);
    scanC<<<391, 256, 0, stream>>>(counts, partial, offs);
    // fused: GEMM1 (writes sup) || packed placement (reads rank_t, writes rec)
    gemm1_place<<<FUSE_GRID, 256, 0, stream>>>(x2, xbf, Wt1, sup, N_NODES, flag,
                                               esrc, edst, ewu, ewf, offs, rank_t, rec);
    agg_pack<<<N_NODES / 4, 256, 0, stream>>>(sup, offs, rec, bb1, h1, out4, flag, 0);
    gemm_gll<<<dim3((N_NODES + 127) / 128, 2), 256, 0, stream>>>(h1, h1, Wt2, sup, N_NODES, flag);
    agg_pack<<<N_NODES / 4, 256, 0, stream>>>(sup, offs, rec, bb2, out2, out4, flag, 1);
    return;
  }

  sniff_kernel<<<1, 256, 0, stream>>>(x2, flag);
  hipMemsetAsync(counts, 0, (size_t)N_NODES * 4, stream);
  prep_all<<<25514, 256, 0, stream>>>(edst, counts, rank, x4, xbf,
                                      W1u, W1f, W2u, W2f, b1u, b1f, b2u, b2f,
                                      flag, Wt1, Wt2, bb1, bb2);
  scanA<<<391, 256, 0, stream>>>(counts, partial);
  scanB<<<1, 512, 0, stream>>>(partial);
  scanC<<<391, 256, 0, stream>>>(counts, partial, offs);

  dim3 ggrid((N_NODES + 127) / 128, 2);

  if (ws_size >= need_split) {
    int* ssrc = (int*)(ws + oTail);
    u16* sw   = (u16*)(ws + oTail + 12800000);
    place_full<<<N_EDGES / 256, 256, 0, stream>>>(esrc, edst, ewu, ewf, flag, offs, rank, ssrc, sw);
    gemm_gll<<<ggrid, 256, 0, stream>>>(x2, xbf, Wt1, sup, N_NODES, flag);
    agg_full<<<N_NODES / 4, 256, 0, stream>>>(sup, offs, ssrc, sw, bb1, h1, out4, flag, 0);
    gemm_gll<<<ggrid, 256, 0, stream>>>(h1, h1, Wt2, sup, N_NODES, flag);
    agg_full<<<N_NODES / 4, 256, 0, stream>>>(sup, offs, ssrc, sw, bb2, out2, out4, flag, 1);
  } else {
    int* seid = (int*)(ws + oTail);
    place_eid<<<N_EDGES / 256, 256, 0, stream>>>(edst, offs, rank, seid);
    gemm_gll<<<ggrid, 256, 0, stream>>>(x2, xbf, Wt1, sup, N_NODES, flag);
    agg_eid<<<N_NODES / 4, 256, 0, stream>>>(sup, offs, seid, esrc, ewu, ewf, bb1, h1, out4, flag, 0);
    gemm_gll<<<ggrid, 256, 0, stream>>>(h1, h1, Wt2, sup, N_NODES, flag);
    agg_eid<<<N_NODES / 4, 256, 0, stream>>>(sup, offs, seid, esrc, ewu, ewf, bb2, out2, out4, flag, 1);
  }
}